// Round 4
// baseline (683.234 us; speedup 1.0000x reference)
//
#include <hip/hip_runtime.h>
#include <math.h>

#define BB 4
#define NN1 4096
#define NN2 1024
#define DS 128
#define DD 64
#define DOUT 256
#define M1 16384        // BB*NN1
#define MH 262144       // M1*16
#define KCAT 192        // DS+DD
#define KI 8            // interp k
#define KN 16           // neighbor k

#define OUT_P1 49152
#define OUT_X  49152
#define OUT_O1 4243456

// ---- workspace layout (float offsets) ----
static const size_t OFF_HPRE = 0;                      // bf16 MH*DS
static const size_t OFF_WTS  = 16777216;               // swizzled weights (hi/lo)
static const size_t OFF_TMP  = 33554432;
static const size_t OFF_XD   = OFF_TMP  + 2097152;
static const size_t OFF_XI   = OFF_XD   + 2097152;
static const size_t OFF_Q    = OFF_XI   + 2097152;
static const size_t OFF_K    = OFF_Q    + 2097152;
static const size_t OFF_V    = OFF_K    + 2097152;
static const size_t OFF_OUTP = OFF_V    + 2097152;
static const size_t OFF_NIDX = OFF_OUTP + 4194304;
static const size_t OFF_STAT = OFF_NIDX + 262144;

// ushort offsets inside the weights region
#define WDH 0
#define WDL 8192
#define WQH 16384
#define WQL 32768
#define WKH 49152
#define WKL 65536
#define WVH 81920
#define WVL 98304
#define W1H 114688
#define W1L 131072
#define W2H 147456
#define W2L 163840
#define WOH 180224
#define WOL 229376

typedef __attribute__((ext_vector_type(8))) short short8;
typedef __attribute__((ext_vector_type(4))) float floatx4;

__device__ inline unsigned short f2bf(float f) {
    union { float f; unsigned int u; } x; x.f = f;
    unsigned int r = x.u + 0x7fffu + ((x.u >> 16) & 1u);
    return (unsigned short)(r >> 16);
}
__device__ inline float bf2f(unsigned short h) {
    union { unsigned int u; float f; } x; x.u = ((unsigned int)h) << 16;
    return x.f;
}
__device__ inline unsigned long long shfl_xor_u64(unsigned long long v, int m) {
    unsigned lo = (unsigned)v, hi = (unsigned)(v >> 32);
    lo = (unsigned)__shfl_xor((int)lo, m);
    hi = (unsigned)__shfl_xor((int)hi, m);
    return ((unsigned long long)hi << 32) | lo;
}

// ---------------------------------------------------------------- copy p1/o1
__global__ void k_copyout(const float* __restrict__ p1, const int* __restrict__ o1,
                          float* __restrict__ out)
{
    int i = blockIdx.x * 256 + threadIdx.x;
    if (i < OUT_P1) out[i] = p1[i];
    else if (i < OUT_P1 + BB) out[OUT_O1 + (i - OUT_P1)] = (float)o1[i - OUT_P1];
}

// --------------------------------------- W swizzle to frag order, hi+lo planes
__global__ __launch_bounds__(64) void k_swizzle_hl(const float* __restrict__ W,
                                                   int N, unsigned short* __restrict__ hi,
                                                   unsigned short* __restrict__ lo)
{
    int fid = blockIdx.x, lane = threadIdx.x;
    int ncj = N >> 4;
    int slab = fid / ncj, cj = fid - slab*ncj;
    int n  = cj*16 + (lane & 15);
    int k0 = slab*32 + (lane >> 4)*8;
    unsigned int oh[8], ol[8];
    #pragma unroll
    for (int j = 0; j < 8; j++) {
        float v = W[(size_t)(k0 + j) * N + n];
        unsigned short h = f2bf(v);
        oh[j] = h;
        ol[j] = f2bf(v - bf2f(h));
    }
    uint4 ph, pl;
    ph.x = oh[0] | (oh[1] << 16); ph.y = oh[2] | (oh[3] << 16);
    ph.z = oh[4] | (oh[5] << 16); ph.w = oh[6] | (oh[7] << 16);
    pl.x = ol[0] | (ol[1] << 16); pl.y = ol[2] | (ol[3] << 16);
    pl.z = ol[4] | (ol[5] << 16); pl.w = ol[6] | (ol[7] << 16);
    ((uint4*)hi)[fid*64 + lane] = ph;
    ((uint4*)lo)[fid*64 + lane] = pl;
}

// ----------------------------- split-bf16 MFMA GEMM (near-fp32 via hi/lo x 3)
template<int N, int K, int MODE>
__global__ __launch_bounds__(256) void k_gemm_mf(
    const float* __restrict__ Amat, const unsigned short* __restrict__ Whi,
    const unsigned short* __restrict__ Wlo, const float* __restrict__ bias,
    float* __restrict__ C, const float* __restrict__ aux)
{
    const int t = threadIdx.x, w = t >> 6, lane = t & 63;
    const int quad = lane >> 4, c = lane & 15;
    const int row = blockIdx.x*64 + w*16 + c;
    const int sA = (MODE == 2) ? DS : K;
    constexpr int nslab = K >> 5;
    constexpr int ncj = N >> 4;
    floatx4 acc[ncj];
    #pragma unroll
    for (int cj = 0; cj < ncj; cj++) acc[cj] = (floatx4){0.f,0.f,0.f,0.f};

    #pragma unroll
    for (int slab = 0; slab < nslab; slab++) {
        const int kk = slab*32 + quad*8;
        const float* src;
        if (MODE == 2 && kk >= DS) src = aux + (size_t)row*DD + (kk - DS);
        else                       src = Amat + (size_t)row*sA + kk;
        floatx4 va = *(const floatx4*)src;
        floatx4 vb = *(const floatx4*)(src + 4);
        short8 ahi, alo;
        #pragma unroll
        for (int j = 0; j < 4; j++) {
            unsigned short h = f2bf(va[j]);
            ahi[j] = (short)h; alo[j] = (short)f2bf(va[j] - bf2f(h));
        }
        #pragma unroll
        for (int j = 0; j < 4; j++) {
            unsigned short h = f2bf(vb[j]);
            ahi[4+j] = (short)h; alo[4+j] = (short)f2bf(vb[j] - bf2f(h));
        }
        const short8* bh = (const short8*)Whi + (size_t)slab*ncj*64;
        const short8* bl = (const short8*)Wlo + (size_t)slab*ncj*64;
        #pragma unroll
        for (int cj = 0; cj < ncj; cj++) {
            short8 bhv = bh[cj*64 + lane];
            short8 blv = bl[cj*64 + lane];
            acc[cj] = __builtin_amdgcn_mfma_f32_16x16x32_bf16(alo, bhv, acc[cj], 0, 0, 0);
            acc[cj] = __builtin_amdgcn_mfma_f32_16x16x32_bf16(ahi, blv, acc[cj], 0, 0, 0);
            acc[cj] = __builtin_amdgcn_mfma_f32_16x16x32_bf16(ahi, bhv, acc[cj], 0, 0, 0);
        }
    }
    const int rbase = blockIdx.x*64 + w*16 + quad*4;
    #pragma unroll
    for (int cj = 0; cj < ncj; cj++) {
        const float bb = bias ? bias[cj*16 + c] : 0.f;
        #pragma unroll
        for (int p = 0; p < 4; p++)
            C[(size_t)(rbase + p)*N + cj*16 + c] = acc[cj][p] + bb;
    }
}

// ------------------------------------------- MFMA h-GEMM + fused BN stats
__global__ __launch_bounds__(256) void k_gemm_h(
    const float* __restrict__ q, const float* __restrict__ km,
    const float* __restrict__ xe, const int* __restrict__ nidx,
    const unsigned short* __restrict__ W1sw, const float* __restrict__ b1,
    unsigned short* __restrict__ hpre,
    float* __restrict__ sums, float* __restrict__ sumsq)
{
    __shared__ unsigned short WF[16384];
    __shared__ unsigned short outT[128*128];
    __shared__ float sstat[256];
    const int t = threadIdx.x;
    const int w = t >> 6, lane = t & 63;
    sstat[t] = 0.f;
    #pragma unroll
    for (int i = 0; i < 8; i++)
        ((uint4*)WF)[t + 256*i] = ((const uint4*)W1sw)[t + 256*i];
    __syncthreads();

    const int quad = lane >> 4, c = lane & 15;
    const int r0 = blockIdx.x * 128 + w * 32;
    const int nid0 = nidx[r0 + c];
    const int nid1 = nidx[r0 + 16 + c];
    const int pr0 = r0 >> 4;
    const int pr1 = pr0 + 1;

    floatx4 acc[2][8];
    #pragma unroll
    for (int ti = 0; ti < 2; ti++)
        #pragma unroll
        for (int cj = 0; cj < 8; cj++)
            acc[ti][cj] = (floatx4){0.f, 0.f, 0.f, 0.f};

    for (int ks = 0; ks < 4; ks++) {
        short8 bf[8];
        #pragma unroll
        for (int cj = 0; cj < 8; cj++)
            bf[cj] = ((const short8*)WF)[(ks*8 + cj)*64 + lane];
        const int ko = ks*32 + quad*8;
        #pragma unroll
        for (int ti = 0; ti < 2; ti++) {
            const int pr = ti ? pr1 : pr0;
            const int m  = ti ? nid1 : nid0;
            const float* qp = q  + (size_t)pr*DS + ko;
            const float* kp = km + (size_t)m*DS + ko;
            const float* xp = xe + (size_t)m*DS + ko;
            floatx4 qa = *(const floatx4*)qp,       qb = *(const floatx4*)(qp+4);
            floatx4 ka = *(const floatx4*)kp,       kb = *(const floatx4*)(kp+4);
            floatx4 xa = *(const floatx4*)xp,       xb = *(const floatx4*)(xp+4);
            short8 af;
            #pragma unroll
            for (int j = 0; j < 4; j++) af[j]   = (short)f2bf(qa[j] - ka[j] + xa[j]);
            #pragma unroll
            for (int j = 0; j < 4; j++) af[4+j] = (short)f2bf(qb[j] - kb[j] + xb[j]);
            #pragma unroll
            for (int cj = 0; cj < 8; cj++)
                acc[ti][cj] = __builtin_amdgcn_mfma_f32_16x16x32_bf16(af, bf[cj], acc[ti][cj], 0, 0, 0);
        }
    }

    #pragma unroll
    for (int cj = 0; cj < 8; cj++) {
        const float bb = b1[cj*16 + c];
        float s = 0.f, ss = 0.f;
        #pragma unroll
        for (int ti = 0; ti < 2; ti++)
            #pragma unroll
            for (int p = 0; p < 4; p++) {
                float v = acc[ti][cj][p] + bb;
                s += v; ss += v*v;
                int lr = w*32 + ti*16 + quad*4 + p;
                outT[lr*128 + cj*16 + c] = f2bf(v);
            }
        s  += __shfl_xor(s, 16);  s  += __shfl_xor(s, 32);
        ss += __shfl_xor(ss, 16); ss += __shfl_xor(ss, 32);
        if (quad == 0) {
            atomicAdd(&sstat[cj*16 + c], s);
            atomicAdd(&sstat[128 + cj*16 + c], ss);
        }
    }
    __syncthreads();
    unsigned short* gdst = hpre + (size_t)blockIdx.x * 128 * 128;
    #pragma unroll
    for (int i = 0; i < 8; i++)
        ((uint4*)gdst)[t + 256*i] = ((const uint4*)outT)[t + 256*i];
    if (t < 128) atomicAdd(&sums[t], sstat[t]);
    else         atomicAdd(&sumsq[t - 128], sstat[t]);
}

// ---------------------------- MFMA attn: bn+relu -> sim GEMM -> softmax -> agg
__global__ __launch_bounds__(256) void k_attn2(
    const unsigned short* __restrict__ hpre, const float* __restrict__ scale_h,
    const float* __restrict__ shift_h, const unsigned short* __restrict__ W2sw,
    const float* __restrict__ v, const float* __restrict__ xe,
    const int* __restrict__ nidx, float* __restrict__ agg)
{
    __shared__ unsigned short WF[16384];
    const int t = threadIdx.x;
    #pragma unroll
    for (int i = 0; i < 8; i++)
        ((uint4*)WF)[t + 256*i] = ((const uint4*)W2sw)[t + 256*i];
    __syncthreads();

    const int w = t >> 6, lane = t & 63;
    const int gp = blockIdx.x * 4 + w;
    const int quad = lane >> 4, c = lane & 15;

    floatx4 acc[8];
    #pragma unroll
    for (int cj = 0; cj < 8; cj++) acc[cj] = (floatx4){0.f, 0.f, 0.f, 0.f};

    for (int ks = 0; ks < 4; ks++) {
        const int ko = ks*32 + quad*8;
        const unsigned short* hp = hpre + ((size_t)gp*16 + c)*DS + ko;
        uint4 hv = *(const uint4*)hp;
        floatx4 sc0 = *(const floatx4*)(scale_h + ko);
        floatx4 sc1 = *(const floatx4*)(scale_h + ko + 4);
        floatx4 sh0 = *(const floatx4*)(shift_h + ko);
        floatx4 sh1 = *(const floatx4*)(shift_h + ko + 4);
        unsigned int hw[4] = {hv.x, hv.y, hv.z, hv.w};
        short8 af;
        #pragma unroll
        for (int j = 0; j < 4; j++) {
            unsigned short u0 = (unsigned short)(hw[j] & 0xffffu);
            unsigned short u1 = (unsigned short)(hw[j] >> 16);
            float f0 = fmaxf(fmaf(bf2f(u0), (j<2)?sc0[2*j]:sc1[2*j-4],   (j<2)?sh0[2*j]:sh1[2*j-4]),   0.f);
            float f1 = fmaxf(fmaf(bf2f(u1), (j<2)?sc0[2*j+1]:sc1[2*j-3], (j<2)?sh0[2*j+1]:sh1[2*j-3]), 0.f);
            af[2*j]   = (short)f2bf(f0);
            af[2*j+1] = (short)f2bf(f1);
        }
        #pragma unroll
        for (int cj = 0; cj < 8; cj++) {
            short8 bfv = ((const short8*)WF)[(ks*8 + cj)*64 + lane];
            acc[cj] = __builtin_amdgcn_mfma_f32_16x16x32_bf16(af, bfv, acc[cj], 0, 0, 0);
        }
    }

    int nid[4];
    #pragma unroll
    for (int p = 0; p < 4; p++) nid[p] = nidx[gp*16 + quad*4 + p];

    #pragma unroll
    for (int cj = 0; cj < 8; cj++) {
        float m4 = fmaxf(fmaxf(acc[cj][0], acc[cj][1]), fmaxf(acc[cj][2], acc[cj][3]));
        m4 = fmaxf(m4, __shfl_xor(m4, 16));
        m4 = fmaxf(m4, __shfl_xor(m4, 32));
        float e[4]; float s4 = 0.f;
        #pragma unroll
        for (int p = 0; p < 4; p++) { e[p] = __expf(acc[cj][p] - m4); s4 += e[p]; }
        s4 += __shfl_xor(s4, 16); s4 += __shfl_xor(s4, 32);
        const float inv = 1.f / s4;
        const int col = cj*16 + c;
        float a = 0.f;
        #pragma unroll
        for (int p = 0; p < 4; p++) {
            const int m = nid[p];
            a = fmaf(e[p]*inv, v[(size_t)m*DS + col] + xe[(size_t)m*DS + col], a);
        }
        a += __shfl_xor(a, 16); a += __shfl_xor(a, 32);
        if (quad == 0) agg[(size_t)gp*DS + col] = a;
    }
}

// ---------------------------------------------------------------- column stats
__global__ __launch_bounds__(256) void k_colstats(
    const float* __restrict__ X, int M, int N,
    float* __restrict__ sums, float* __restrict__ sumsq)
{
    __shared__ float sh[256], sh2[256];
    int t = threadIdx.x;
    int c = t & (N - 1);
    int rl = t / N;
    int stride = 256 / N;
    int rowsPerBlk = (M + gridDim.x - 1) / gridDim.x;
    int r0 = blockIdx.x * rowsPerBlk;
    int r1 = min(M, r0 + rowsPerBlk);
    float s = 0.f, ss = 0.f;
    for (int r = r0 + rl; r < r1; r += stride) {
        float v = X[(size_t)r*N + c];
        s += v; ss += v*v;
    }
    sh[t] = s; sh2[t] = ss;
    __syncthreads();
    if (t < N) {
        for (int i = 1; i < stride; i++) { s += sh[t + i*N]; ss += sh2[t + i*N]; }
        atomicAdd(&sums[c], s);
        atomicAdd(&sumsq[c], ss);
    }
}

__global__ void k_finalize(const float* __restrict__ sums, const float* __restrict__ sumsq,
                           const float* __restrict__ g, const float* __restrict__ bt,
                           int M, int N, float* __restrict__ scale, float* __restrict__ shift)
{
    int c = blockIdx.x * blockDim.x + threadIdx.x;
    if (c < N) {
        float m  = sums[c] / (float)M;
        float var = sumsq[c] / (float)M - m*m;
        float sc = g[c] * rsqrtf(var + 1e-5f);
        scale[c] = sc;
        shift[c] = bt[c] - m * sc;
    }
}

__global__ __launch_bounds__(256) void k_bnrelu(
    const float* __restrict__ X, const float* __restrict__ scale,
    const float* __restrict__ shift, float* __restrict__ Y, size_t total, int N)
{
    size_t i = (size_t)blockIdx.x * 256 + threadIdx.x;
    if (i < total) {
        int c = (int)(i & (size_t)(N - 1));
        Y[i] = fmaxf(fmaf(X[i], scale[c], shift[c]), 0.f);
    }
}

// --------------------- cooperative block radix-select top-K (256 threads/query)
// EPI 0: write nidx (K=16).  EPI 1: inverse-distance interp (K=8) -> xi.
template<int NCAND, int KSEL, int EPI>
__global__ __launch_bounds__(256) void k_sel(
    const float* __restrict__ qpts, const float* __restrict__ cpts,
    int* __restrict__ nidx, const float* __restrict__ x2, float* __restrict__ xi)
{
    __shared__ unsigned keys[NCAND];
    __shared__ unsigned hist[1024];          // 4 per-wave sub-hists
    __shared__ unsigned skey[64];
    __shared__ unsigned sidx[64];
    __shared__ float    swt[KSEL];
    __shared__ int      sstate[8];           // pfx,S,cntB,shift,mode,cnt,total

    const int gp = blockIdx.x, b = gp >> 12;
    const int t = threadIdx.x, wv = t >> 6, lane = t & 63;
    const float px = qpts[gp*3+0], py = qpts[gp*3+1], pz = qpts[gp*3+2];
    const float sa = px*px + py*py + pz*pz;
    const float* pb = cpts + (size_t)b*NCAND*3;
    constexpr int ITER = NCAND / 256;

    #pragma unroll
    for (int it = 0; it < ITER; it++) {
        int j = t + 256*it;
        float qx = pb[j*3+0], qy = pb[j*3+1], qz = pb[j*3+2];
        float sb  = qx*qx + qy*qy + qz*qz;
        float dot = px*qx + py*qy + pz*qz;
        float d = sqrtf(fmaxf((sa + sb) - 2.f*dot, 0.f));
        keys[j] = __float_as_uint(d);
    }

    unsigned pfx = 0;
    int S = 0, cntB = 0, shift = 24, gsh = 0, mode = 0;
    for (int round = 0; round < 4; round++) {
        ((uint4*)hist)[t] = (uint4){0u,0u,0u,0u};
        __syncthreads();
        const unsigned pmask = (round == 0) ? 0u : (0xFFFFFFFFu << (shift + 8));
        #pragma unroll
        for (int it = 0; it < ITER; it++) {
            unsigned key = keys[t + 256*it];
            if ((key & pmask) == pfx)
                atomicAdd(&hist[wv*256 + ((key >> shift) & 255)], 1u);
        }
        __syncthreads();
        hist[t] = hist[t] + hist[256+t] + hist[512+t] + hist[768+t];
        __syncthreads();
        if (t < 64) {
            uint4 h4 = ((uint4*)hist)[lane];
            unsigned hv[4] = {h4.x, h4.y, h4.z, h4.w};
            unsigned s4 = hv[0] + hv[1] + hv[2] + hv[3];
            unsigned incl = s4;
            #pragma unroll
            for (int off = 1; off < 64; off <<= 1) {
                unsigned o = __shfl_up(incl, off);
                if (lane >= off) incl += o;
            }
            unsigned excl = incl - s4;
            const int need = KSEL - S;
            int which = -1; unsigned below = 0;
            unsigned cum = excl;
            #pragma unroll
            for (int i = 0; i < 4; i++) {
                if (which < 0 && (int)cum < need && need <= (int)(cum + hv[i])) { which = i; below = cum; }
                cum += hv[i];
            }
            unsigned long long bal = __ballot(which >= 0);
            int src = __ffsll((unsigned long long)bal) - 1;
            int Bbin = __shfl(which, src) + src*4;
            unsigned belowB = (unsigned)__shfl((int)below, src);
            if (lane == 0) {
                int nS = S + (int)belowB;
                int nB = (int)hist[Bbin];
                unsigned npfx = pfx | (((unsigned)Bbin) << shift);
                int md = 0;
                if (nS + nB <= 64) md = 1;
                else if (shift == 0) md = 2;
                sstate[0] = (int)npfx; sstate[1] = nS; sstate[2] = nB;
                sstate[3] = shift; sstate[4] = md; sstate[5] = 0;
            }
        }
        __syncthreads();
        pfx = (unsigned)sstate[0]; S = sstate[1]; cntB = sstate[2];
        gsh = sstate[3]; mode = sstate[4];
        if (mode) break;
        shift = gsh - 8;
        __syncthreads();
    }

    int total;
    if (mode != 2) {
        // unordered block compaction (bitonic sort restores (key,idx) order)
        const unsigned P = pfx >> gsh;
        const unsigned long long lmask = (1ull << lane) - 1ull;
        #pragma unroll
        for (int it = 0; it < ITER; it++) {
            int j = t + 256*it;
            unsigned key = keys[j];
            bool f = ((key >> gsh) <= P);
            unsigned long long bal = __ballot(f);
            int wcnt = __popcll(bal);
            int base = 0;
            if (lane == 0 && wcnt) base = atomicAdd((unsigned*)&sstate[5], (unsigned)wcnt);
            base = __shfl(base, 0);
            if (f) {
                int pos = base + __popcll(bal & lmask);
                skey[pos] = key; sidx[pos] = (unsigned)j;
            }
        }
        total = S + cntB;
    } else {
        // rare exact-tie overflow: wave 0 serial, definite-ins then ties by index
        if (t < 64) {
            const unsigned long long lmask = (1ull << lane) - 1ull;
            int cnt = 0;
            for (int it = 0; it < NCAND/64; it++) {
                int j = lane + 64*it;
                unsigned key = keys[j];
                bool f = (key < pfx);
                unsigned long long bal = __ballot(f);
                if (f) { int pos = cnt + __popcll(bal & lmask); skey[pos] = key; sidx[pos] = (unsigned)j; }
                cnt += __popcll(bal);
            }
            for (int it = 0; it < NCAND/64; it++) {
                int j = lane + 64*it;
                unsigned key = keys[j];
                bool f = (key == pfx);
                unsigned long long bal = __ballot(f);
                if (f) {
                    int pos = cnt + __popcll(bal & lmask);
                    if (pos < 64) { skey[pos] = key; sidx[pos] = (unsigned)j; }
                }
                cnt += __popcll(bal);
            }
            if (lane == 0) sstate[6] = min(cnt, 64);
        }
        __syncthreads();
        total = sstate[6];
    }
    __syncthreads();

    // 64-lane bitonic sort on wave 0: (key, idx) ascending
    if (t < 64) {
        unsigned long long v = ~0ull;
        if (lane < total) v = (((unsigned long long)skey[lane]) << 32) | sidx[lane];
        #pragma unroll
        for (int k = 2; k <= 64; k <<= 1) {
            #pragma unroll
            for (int jj = k >> 1; jj > 0; jj >>= 1) {
                unsigned long long p = shfl_xor_u64(v, jj);
                bool up = ((lane & k) == 0);
                bool takeMin = (((lane & jj) == 0) == up);
                bool pl = p < v;
                v = (takeMin == pl) ? p : v;
            }
        }
        if (EPI == 0) {
            if (lane < KSEL)
                nidx[gp*KSEL + lane] = b*NCAND + (int)(v & 0xffffffffull);
        } else {
            float w = 0.f;
            if (lane < KSEL)
                w = 1.f / (__uint_as_float((unsigned)(v >> 32)) + 1e-8f);
            float ws = w;
            ws += __shfl_xor(ws, 1); ws += __shfl_xor(ws, 2); ws += __shfl_xor(ws, 4);
            if (lane < KSEL) {
                swt[lane]  = w / ws;
                sidx[lane] = (unsigned)(v & 0xffffffffull);
            }
        }
    }
    if (EPI == 1) {
        __syncthreads();
        if (t < DS) {
            const float* x2b = x2 + (size_t)b*NCAND*DS;
            float a = 0.f;
            #pragma unroll
            for (int r = 0; r < KSEL; r++)
                a = fmaf(swt[r], x2b[(size_t)sidx[r]*DS + t], a);
            xi[(size_t)gp*DS + t] = a;
        }
    }
}

// ---------------------------------------------------------------- launch
extern "C" void kernel_launch(void* const* d_in, const int* in_sizes, int n_in,
                              void* d_out, int out_size, void* d_ws, size_t ws_size,
                              hipStream_t stream)
{
    const float* p1 = (const float*)d_in[0];
    const float* x1 = (const float*)d_in[1];
    const int*   o1 = (const int*)d_in[2];
    const float* p2 = (const float*)d_in[3];
    const float* x2 = (const float*)d_in[4];
    const float* W_dense = (const float*)d_in[7];
    const float* b_dense = (const float*)d_in[8];
    const float* g_dense = (const float*)d_in[9];
    const float* bt_dense= (const float*)d_in[10];
    const float* Wq = (const float*)d_in[11];
    const float* Wk = (const float*)d_in[12];
    const float* Wv = (const float*)d_in[13];
    const float* W1 = (const float*)d_in[14];
    const float* b1 = (const float*)d_in[15];
    const float* g1 = (const float*)d_in[16];
    const float* bt1= (const float*)d_in[17];
    const float* W2 = (const float*)d_in[18];
    const float* W_out = (const float*)d_in[20];
    const float* b_out = (const float*)d_in[21];
    const float* g_out = (const float*)d_in[22];
    const float* bt_out= (const float*)d_in[23];

    float* ws   = (float*)d_ws;
    unsigned short* hpre = (unsigned short*)(ws + OFF_HPRE);
    unsigned short* wts  = (unsigned short*)(ws + OFF_WTS);
    float* tmp  = ws + OFF_TMP;
    float* xd   = ws + OFF_XD;
    float* xi   = ws + OFF_XI;
    float* qm   = ws + OFF_Q;
    float* km   = ws + OFF_K;
    float* vm   = ws + OFF_V;
    float* outp = ws + OFF_OUTP;
    int*   nidx = (int*)(ws + OFF_NIDX);
    float* stat = ws + OFF_STAT;
    float* sums_d = stat,      *sumsq_d = stat+256,  *scale_d = stat+512,  *shift_d = stat+768;
    float* sums_h = stat+1024, *sumsq_h = stat+1280, *scale_h = stat+1536, *shift_h = stat+1792;
    float* sums_o = stat+2048, *sumsq_o = stat+2304, *scale_o = stat+2560, *shift_o = stat+2816;
    float* out = (float*)d_out;

    hipMemsetAsync(stat, 0, 3*1024*sizeof(float), stream);
    k_copyout<<<(OUT_P1 + BB + 255)/256, 256, 0, stream>>>(p1, o1, out);

    // weight swizzles (hi/lo planes)
    k_swizzle_hl<<<16, 64, 0, stream>>>(W_dense, 128, wts+WDH, wts+WDL);
    k_swizzle_hl<<<32, 64, 0, stream>>>(Wq, 128, wts+WQH, wts+WQL);
    k_swizzle_hl<<<32, 64, 0, stream>>>(Wk, 128, wts+WKH, wts+WKL);
    k_swizzle_hl<<<32, 64, 0, stream>>>(Wv, 128, wts+WVH, wts+WVL);
    k_swizzle_hl<<<32, 64, 0, stream>>>(W1, 128, wts+W1H, wts+W1L);
    k_swizzle_hl<<<32, 64, 0, stream>>>(W2, 128, wts+W2H, wts+W2L);
    k_swizzle_hl<<<96, 64, 0, stream>>>(W_out, 256, wts+WOH, wts+WOL);

    // dense_mlp
    k_gemm_mf<128,64,0><<<M1/64, 256, 0, stream>>>(x1, wts+WDH, wts+WDL, b_dense, tmp, nullptr);
    k_colstats<<<128, 256, 0, stream>>>(tmp, M1, DS, sums_d, sumsq_d);
    k_finalize<<<1, 256, 0, stream>>>(sums_d, sumsq_d, g_dense, bt_dense, M1, DS, scale_d, shift_d);
    k_bnrelu<<<(M1*DS)/256, 256, 0, stream>>>(tmp, scale_d, shift_d, xd, (size_t)M1*DS, DS);

    // interpolation (cooperative radix select, K=8)
    k_sel<NN2, KI, 1><<<M1, 256, 0, stream>>>(p1, p2, nullptr, x2, xi);

    // q, k, v projections
    k_gemm_mf<128,128,0><<<M1/64, 256, 0, stream>>>(xd, wts+WQH, wts+WQL, nullptr, qm, nullptr);
    k_gemm_mf<128,128,0><<<M1/64, 256, 0, stream>>>(xi, wts+WKH, wts+WKL, nullptr, km, nullptr);
    k_gemm_mf<128,128,0><<<M1/64, 256, 0, stream>>>(xi, wts+WVH, wts+WVL, nullptr, vm, nullptr);

    // kNN-16 (cooperative radix select)
    k_sel<NN1, KN, 0><<<M1, 256, 0, stream>>>(p1, p1, nidx, nullptr, nullptr);

    // h-GEMM (MFMA, fused BN stats) -> hpre bf16
    k_gemm_h<<<MH/128, 256, 0, stream>>>(qm, km, xd, nidx, wts+W1H, b1, hpre, sums_h, sumsq_h);
    k_finalize<<<1, 256, 0, stream>>>(sums_h, sumsq_h, g1, bt1, MH, DS, scale_h, shift_h);

    // attn (MFMA)
    k_attn2<<<M1/4, 256, 0, stream>>>(hpre, scale_h, shift_h, wts+W2H, vm, xd, nidx, tmp);

    // output mlp
    k_gemm_mf<256,192,2><<<M1/64, 256, 0, stream>>>(tmp, wts+WOH, wts+WOL, b_out, outp, x1);
    k_colstats<<<128, 256, 0, stream>>>(outp, M1, DOUT, sums_o, sumsq_o);
    k_finalize<<<1, 256, 0, stream>>>(sums_o, sumsq_o, g_out, bt_out, M1, DOUT, scale_o, shift_o);
    k_bnrelu<<<(M1*DOUT)/256, 256, 0, stream>>>(outp, scale_o, shift_o, out + OUT_X,
        (size_t)M1*DOUT, DOUT);
}

// Round 5
// 573.704 us; speedup vs baseline: 1.1909x; 1.1909x over previous
//
#include <hip/hip_runtime.h>
#include <math.h>

#define BB 4
#define NN1 4096
#define NN2 1024
#define DS 128
#define DD 64
#define DOUT 256
#define M1 16384        // BB*NN1
#define MH 262144       // M1*16
#define KCAT 192        // DS+DD
#define KI 8            // interp k
#define KN 16           // neighbor k

#define OUT_P1 49152
#define OUT_X  49152
#define OUT_O1 4243456

// ---- workspace layout (float offsets) ----
static const size_t OFF_HPRE = 0;                      // bf16 MH*DS
static const size_t OFF_WTS  = 16777216;               // swizzled weights (hi/lo)
static const size_t OFF_TMP  = 33554432;
static const size_t OFF_XD   = OFF_TMP  + 2097152;
static const size_t OFF_XI   = OFF_XD   + 2097152;
static const size_t OFF_Q    = OFF_XI   + 2097152;
static const size_t OFF_K    = OFF_Q    + 2097152;
static const size_t OFF_V    = OFF_K    + 2097152;
static const size_t OFF_OUTP = OFF_V    + 2097152;
static const size_t OFF_NIDX = OFF_OUTP + 4194304;
static const size_t OFF_STAT = OFF_NIDX + 262144;

// ushort offsets inside the weights region
#define WDH 0
#define WDL 8192
#define WQH 16384
#define WQL 32768
#define WKH 49152
#define WKL 65536
#define WVH 81920
#define WVL 98304
#define W1H 114688
#define W1L 131072
#define W2H 147456
#define W2L 163840
#define WOH 180224
#define WOL 229376

typedef __attribute__((ext_vector_type(8))) short short8;
typedef __attribute__((ext_vector_type(4))) float floatx4;

__device__ inline unsigned short f2bf(float f) {
    union { float f; unsigned int u; } x; x.f = f;
    unsigned int r = x.u + 0x7fffu + ((x.u >> 16) & 1u);
    return (unsigned short)(r >> 16);
}
__device__ inline float bf2f(unsigned short h) {
    union { unsigned int u; float f; } x; x.u = ((unsigned int)h) << 16;
    return x.f;
}
__device__ inline unsigned long long shfl_xor_u64(unsigned long long v, int m) {
    unsigned lo = (unsigned)v, hi = (unsigned)(v >> 32);
    lo = (unsigned)__shfl_xor((int)lo, m);
    hi = (unsigned)__shfl_xor((int)hi, m);
    return ((unsigned long long)hi << 32) | lo;
}

// ---------------------------------------------------------------- copy p1/o1
__global__ void k_copyout(const float* __restrict__ p1, const int* __restrict__ o1,
                          float* __restrict__ out)
{
    int i = blockIdx.x * 256 + threadIdx.x;
    if (i < OUT_P1) out[i] = p1[i];
    else if (i < OUT_P1 + BB) out[OUT_O1 + (i - OUT_P1)] = (float)o1[i - OUT_P1];
}

// --------------------------------------- W swizzle to frag order, hi+lo planes
__global__ __launch_bounds__(64) void k_swizzle_hl(const float* __restrict__ W,
                                                   int N, unsigned short* __restrict__ hi,
                                                   unsigned short* __restrict__ lo)
{
    int fid = blockIdx.x, lane = threadIdx.x;
    int ncj = N >> 4;
    int slab = fid / ncj, cj = fid - slab*ncj;
    int n  = cj*16 + (lane & 15);
    int k0 = slab*32 + (lane >> 4)*8;
    unsigned int oh[8], ol[8];
    #pragma unroll
    for (int j = 0; j < 8; j++) {
        float v = W[(size_t)(k0 + j) * N + n];
        unsigned short h = f2bf(v);
        oh[j] = h;
        ol[j] = f2bf(v - bf2f(h));
    }
    uint4 ph, pl;
    ph.x = oh[0] | (oh[1] << 16); ph.y = oh[2] | (oh[3] << 16);
    ph.z = oh[4] | (oh[5] << 16); ph.w = oh[6] | (oh[7] << 16);
    pl.x = ol[0] | (ol[1] << 16); pl.y = ol[2] | (ol[3] << 16);
    pl.z = ol[4] | (ol[5] << 16); pl.w = ol[6] | (ol[7] << 16);
    ((uint4*)hi)[fid*64 + lane] = ph;
    ((uint4*)lo)[fid*64 + lane] = pl;
}

// ----------------------------- split-bf16 MFMA GEMM (near-fp32 via hi/lo x 3)
template<int N, int K, int MODE>
__global__ __launch_bounds__(256) void k_gemm_mf(
    const float* __restrict__ Amat, const unsigned short* __restrict__ Whi,
    const unsigned short* __restrict__ Wlo, const float* __restrict__ bias,
    float* __restrict__ C, const float* __restrict__ aux)
{
    const int t = threadIdx.x, w = t >> 6, lane = t & 63;
    const int quad = lane >> 4, c = lane & 15;
    const int row = blockIdx.x*64 + w*16 + c;
    const int sA = (MODE == 2) ? DS : K;
    constexpr int nslab = K >> 5;
    constexpr int ncj = N >> 4;
    floatx4 acc[ncj];
    #pragma unroll
    for (int cj = 0; cj < ncj; cj++) acc[cj] = (floatx4){0.f,0.f,0.f,0.f};

    #pragma unroll
    for (int slab = 0; slab < nslab; slab++) {
        const int kk = slab*32 + quad*8;
        const float* src;
        if (MODE == 2 && kk >= DS) src = aux + (size_t)row*DD + (kk - DS);
        else                       src = Amat + (size_t)row*sA + kk;
        floatx4 va = *(const floatx4*)src;
        floatx4 vb = *(const floatx4*)(src + 4);
        short8 ahi, alo;
        #pragma unroll
        for (int j = 0; j < 4; j++) {
            unsigned short h = f2bf(va[j]);
            ahi[j] = (short)h; alo[j] = (short)f2bf(va[j] - bf2f(h));
        }
        #pragma unroll
        for (int j = 0; j < 4; j++) {
            unsigned short h = f2bf(vb[j]);
            ahi[4+j] = (short)h; alo[4+j] = (short)f2bf(vb[j] - bf2f(h));
        }
        const short8* bh = (const short8*)Whi + (size_t)slab*ncj*64;
        const short8* bl = (const short8*)Wlo + (size_t)slab*ncj*64;
        #pragma unroll
        for (int cj = 0; cj < ncj; cj++) {
            short8 bhv = bh[cj*64 + lane];
            short8 blv = bl[cj*64 + lane];
            acc[cj] = __builtin_amdgcn_mfma_f32_16x16x32_bf16(alo, bhv, acc[cj], 0, 0, 0);
            acc[cj] = __builtin_amdgcn_mfma_f32_16x16x32_bf16(ahi, blv, acc[cj], 0, 0, 0);
            acc[cj] = __builtin_amdgcn_mfma_f32_16x16x32_bf16(ahi, bhv, acc[cj], 0, 0, 0);
        }
    }
    const int rbase = blockIdx.x*64 + w*16 + quad*4;
    #pragma unroll
    for (int cj = 0; cj < ncj; cj++) {
        const float bb = bias ? bias[cj*16 + c] : 0.f;
        #pragma unroll
        for (int p = 0; p < 4; p++)
            C[(size_t)(rbase + p)*N + cj*16 + c] = acc[cj][p] + bb;
    }
}

// ------------------------------------------- MFMA h-GEMM + fused BN stats
__global__ __launch_bounds__(256) void k_gemm_h(
    const float* __restrict__ q, const float* __restrict__ km,
    const float* __restrict__ xe, const int* __restrict__ nidx,
    const unsigned short* __restrict__ W1sw, const float* __restrict__ b1,
    unsigned short* __restrict__ hpre,
    float* __restrict__ sums, float* __restrict__ sumsq)
{
    __shared__ unsigned short WF[16384];
    __shared__ unsigned short outT[128*128];
    __shared__ float sstat[256];
    const int t = threadIdx.x;
    const int w = t >> 6, lane = t & 63;
    sstat[t] = 0.f;
    #pragma unroll
    for (int i = 0; i < 8; i++)
        ((uint4*)WF)[t + 256*i] = ((const uint4*)W1sw)[t + 256*i];
    __syncthreads();

    const int quad = lane >> 4, c = lane & 15;
    const int r0 = blockIdx.x * 128 + w * 32;
    const int nid0 = nidx[r0 + c];
    const int nid1 = nidx[r0 + 16 + c];
    const int pr0 = r0 >> 4;
    const int pr1 = pr0 + 1;

    floatx4 acc[2][8];
    #pragma unroll
    for (int ti = 0; ti < 2; ti++)
        #pragma unroll
        for (int cj = 0; cj < 8; cj++)
            acc[ti][cj] = (floatx4){0.f, 0.f, 0.f, 0.f};

    for (int ks = 0; ks < 4; ks++) {
        short8 bf[8];
        #pragma unroll
        for (int cj = 0; cj < 8; cj++)
            bf[cj] = ((const short8*)WF)[(ks*8 + cj)*64 + lane];
        const int ko = ks*32 + quad*8;
        #pragma unroll
        for (int ti = 0; ti < 2; ti++) {
            const int pr = ti ? pr1 : pr0;
            const int m  = ti ? nid1 : nid0;
            const float* qp = q  + (size_t)pr*DS + ko;
            const float* kp = km + (size_t)m*DS + ko;
            const float* xp = xe + (size_t)m*DS + ko;
            floatx4 qa = *(const floatx4*)qp,       qb = *(const floatx4*)(qp+4);
            floatx4 ka = *(const floatx4*)kp,       kb = *(const floatx4*)(kp+4);
            floatx4 xa = *(const floatx4*)xp,       xb = *(const floatx4*)(xp+4);
            short8 af;
            #pragma unroll
            for (int j = 0; j < 4; j++) af[j]   = (short)f2bf(qa[j] - ka[j] + xa[j]);
            #pragma unroll
            for (int j = 0; j < 4; j++) af[4+j] = (short)f2bf(qb[j] - kb[j] + xb[j]);
            #pragma unroll
            for (int cj = 0; cj < 8; cj++)
                acc[ti][cj] = __builtin_amdgcn_mfma_f32_16x16x32_bf16(af, bf[cj], acc[ti][cj], 0, 0, 0);
        }
    }

    #pragma unroll
    for (int cj = 0; cj < 8; cj++) {
        const float bb = b1[cj*16 + c];
        float s = 0.f, ss = 0.f;
        #pragma unroll
        for (int ti = 0; ti < 2; ti++)
            #pragma unroll
            for (int p = 0; p < 4; p++) {
                float v = acc[ti][cj][p] + bb;
                s += v; ss += v*v;
                int lr = w*32 + ti*16 + quad*4 + p;
                outT[lr*128 + cj*16 + c] = f2bf(v);
            }
        s  += __shfl_xor(s, 16);  s  += __shfl_xor(s, 32);
        ss += __shfl_xor(ss, 16); ss += __shfl_xor(ss, 32);
        if (quad == 0) {
            atomicAdd(&sstat[cj*16 + c], s);
            atomicAdd(&sstat[128 + cj*16 + c], ss);
        }
    }
    __syncthreads();
    unsigned short* gdst = hpre + (size_t)blockIdx.x * 128 * 128;
    #pragma unroll
    for (int i = 0; i < 8; i++)
        ((uint4*)gdst)[t + 256*i] = ((const uint4*)outT)[t + 256*i];
    if (t < 128) atomicAdd(&sums[t], sstat[t]);
    else         atomicAdd(&sumsq[t - 128], sstat[t]);
}

// ---------------------------- MFMA attn: bn+relu -> sim GEMM -> softmax -> agg
__global__ __launch_bounds__(256) void k_attn2(
    const unsigned short* __restrict__ hpre, const float* __restrict__ scale_h,
    const float* __restrict__ shift_h, const unsigned short* __restrict__ W2sw,
    const float* __restrict__ v, const float* __restrict__ xe,
    const int* __restrict__ nidx, float* __restrict__ agg)
{
    __shared__ unsigned short WF[16384];
    const int t = threadIdx.x;
    #pragma unroll
    for (int i = 0; i < 8; i++)
        ((uint4*)WF)[t + 256*i] = ((const uint4*)W2sw)[t + 256*i];
    __syncthreads();

    const int w = t >> 6, lane = t & 63;
    const int gp = blockIdx.x * 4 + w;
    const int quad = lane >> 4, c = lane & 15;

    floatx4 acc[8];
    #pragma unroll
    for (int cj = 0; cj < 8; cj++) acc[cj] = (floatx4){0.f, 0.f, 0.f, 0.f};

    for (int ks = 0; ks < 4; ks++) {
        const int ko = ks*32 + quad*8;
        const unsigned short* hp = hpre + ((size_t)gp*16 + c)*DS + ko;
        uint4 hv = *(const uint4*)hp;
        floatx4 sc0 = *(const floatx4*)(scale_h + ko);
        floatx4 sc1 = *(const floatx4*)(scale_h + ko + 4);
        floatx4 sh0 = *(const floatx4*)(shift_h + ko);
        floatx4 sh1 = *(const floatx4*)(shift_h + ko + 4);
        unsigned int hw[4] = {hv.x, hv.y, hv.z, hv.w};
        short8 af;
        #pragma unroll
        for (int j = 0; j < 4; j++) {
            unsigned short u0 = (unsigned short)(hw[j] & 0xffffu);
            unsigned short u1 = (unsigned short)(hw[j] >> 16);
            float f0 = fmaxf(fmaf(bf2f(u0), (j<2)?sc0[2*j]:sc1[2*j-4],   (j<2)?sh0[2*j]:sh1[2*j-4]),   0.f);
            float f1 = fmaxf(fmaf(bf2f(u1), (j<2)?sc0[2*j+1]:sc1[2*j-3], (j<2)?sh0[2*j+1]:sh1[2*j-3]), 0.f);
            af[2*j]   = (short)f2bf(f0);
            af[2*j+1] = (short)f2bf(f1);
        }
        #pragma unroll
        for (int cj = 0; cj < 8; cj++) {
            short8 bfv = ((const short8*)WF)[(ks*8 + cj)*64 + lane];
            acc[cj] = __builtin_amdgcn_mfma_f32_16x16x32_bf16(af, bfv, acc[cj], 0, 0, 0);
        }
    }

    int nid[4];
    #pragma unroll
    for (int p = 0; p < 4; p++) nid[p] = nidx[gp*16 + quad*4 + p];

    #pragma unroll
    for (int cj = 0; cj < 8; cj++) {
        float m4 = fmaxf(fmaxf(acc[cj][0], acc[cj][1]), fmaxf(acc[cj][2], acc[cj][3]));
        m4 = fmaxf(m4, __shfl_xor(m4, 16));
        m4 = fmaxf(m4, __shfl_xor(m4, 32));
        float e[4]; float s4 = 0.f;
        #pragma unroll
        for (int p = 0; p < 4; p++) { e[p] = __expf(acc[cj][p] - m4); s4 += e[p]; }
        s4 += __shfl_xor(s4, 16); s4 += __shfl_xor(s4, 32);
        const float inv = 1.f / s4;
        const int col = cj*16 + c;
        float a = 0.f;
        #pragma unroll
        for (int p = 0; p < 4; p++) {
            const int m = nid[p];
            a = fmaf(e[p]*inv, v[(size_t)m*DS + col] + xe[(size_t)m*DS + col], a);
        }
        a += __shfl_xor(a, 16); a += __shfl_xor(a, 32);
        if (quad == 0) agg[(size_t)gp*DS + col] = a;
    }
}

// ---------------------------------------------------------------- column stats
__global__ __launch_bounds__(256) void k_colstats(
    const float* __restrict__ X, int M, int N,
    float* __restrict__ sums, float* __restrict__ sumsq)
{
    __shared__ float sh[256], sh2[256];
    int t = threadIdx.x;
    int c = t & (N - 1);
    int rl = t / N;
    int stride = 256 / N;
    int rowsPerBlk = (M + gridDim.x - 1) / gridDim.x;
    int r0 = blockIdx.x * rowsPerBlk;
    int r1 = min(M, r0 + rowsPerBlk);
    float s = 0.f, ss = 0.f;
    for (int r = r0 + rl; r < r1; r += stride) {
        float v = X[(size_t)r*N + c];
        s += v; ss += v*v;
    }
    sh[t] = s; sh2[t] = ss;
    __syncthreads();
    if (t < N) {
        for (int i = 1; i < stride; i++) { s += sh[t + i*N]; ss += sh2[t + i*N]; }
        atomicAdd(&sums[c], s);
        atomicAdd(&sumsq[c], ss);
    }
}

__global__ void k_finalize(const float* __restrict__ sums, const float* __restrict__ sumsq,
                           const float* __restrict__ g, const float* __restrict__ bt,
                           int M, int N, float* __restrict__ scale, float* __restrict__ shift)
{
    int c = blockIdx.x * blockDim.x + threadIdx.x;
    if (c < N) {
        float m  = sums[c] / (float)M;
        float var = sumsq[c] / (float)M - m*m;
        float sc = g[c] * rsqrtf(var + 1e-5f);
        scale[c] = sc;
        shift[c] = bt[c] - m * sc;
    }
}

__global__ __launch_bounds__(256) void k_bnrelu(
    const float* __restrict__ X, const float* __restrict__ scale,
    const float* __restrict__ shift, float* __restrict__ Y, size_t total, int N)
{
    size_t i = (size_t)blockIdx.x * 256 + threadIdx.x;
    if (i < total) {
        int c = (int)(i & (size_t)(N - 1));
        Y[i] = fmaxf(fmaf(X[i], scale[c], shift[c]), 0.f);
    }
}

// --------------- cooperative radix-select top-K, 12-bit spread digits
// rounds on float-d bits: [31:20] (4096 bins), [19:8] (4096), [7:0] (256)
// EPI 0: write nidx (K=16).  EPI 1: inverse-distance interp (K=8) -> xi.
template<int NCAND, int KSEL, int EPI>
__global__ __launch_bounds__(256) void k_sel(
    const float* __restrict__ qpts, const float* __restrict__ cpts,
    int* __restrict__ nidx, const float* __restrict__ x2, float* __restrict__ xi)
{
    __shared__ unsigned keys[NCAND];
    __shared__ unsigned hist[4096];
    __shared__ unsigned skey[64];
    __shared__ unsigned sidx[64];
    __shared__ float    swt[KSEL];
    __shared__ unsigned wpart[4];
    __shared__ int      sstate[8];   // P,S,cntB,mode,compact-counter,total

    const int gp = blockIdx.x, b = gp >> 12;
    const int t = threadIdx.x, wv = t >> 6, lane = t & 63;
    constexpr int ITER = NCAND / 256;

    const float px = qpts[gp*3+0], py = qpts[gp*3+1], pz = qpts[gp*3+2];
    const float sa = px*px + py*py + pz*pz;
    const float* pb = cpts + (size_t)b*NCAND*3;

    #pragma unroll
    for (int it = 0; it < ITER; it++) {
        int j = t + 256*it;
        float qx = pb[j*3+0], qy = pb[j*3+1], qz = pb[j*3+2];
        float sb  = qx*qx + qy*qy + qz*qz;
        float dot = px*qx + py*qy + pz*qz;
        float d = sqrtf(fmaxf((sa + sb) - 2.f*dot, 0.f));
        keys[j] = __float_as_uint(d);
    }

    unsigned P = 0;
    int S = 0, cntB = 0, mode = 0, gsh = 0;
    for (int round = 0; round < 3; round++) {
        const int nb  = (round < 2) ? 4096 : 256;
        const int bpt = nb >> 8;
        const int wb  = (round < 2) ? 12 : 8;
        const int sh  = (round == 0) ? 20 : (round == 1 ? 8 : 0);
        const int psh = (sh + wb) & 31;
        for (int i2 = t; i2 < (nb >> 2); i2 += 256)
            ((uint4*)hist)[i2] = (uint4){0u,0u,0u,0u};
        __syncthreads();
        #pragma unroll
        for (int it = 0; it < ITER; it++) {
            unsigned key = keys[t + 256*it];
            bool act = (round == 0) ? true : ((key >> psh) == P);
            if (act) atomicAdd(&hist[(key >> sh) & (nb - 1)], 1u);
        }
        __syncthreads();
        unsigned hv[16]; unsigned tsum = 0;
        if (bpt == 16) {
            #pragma unroll
            for (int qq = 0; qq < 4; qq++) {
                uint4 h4 = ((const uint4*)hist)[t*4 + qq];
                hv[qq*4+0]=h4.x; hv[qq*4+1]=h4.y; hv[qq*4+2]=h4.z; hv[qq*4+3]=h4.w;
            }
            #pragma unroll
            for (int qq = 0; qq < 16; qq++) tsum += hv[qq];
        } else {
            hv[0] = hist[t]; tsum = hv[0];
        }
        unsigned incl = tsum;
        #pragma unroll
        for (int off = 1; off < 64; off <<= 1) {
            unsigned o = (unsigned)__shfl_up((int)incl, off);
            if (lane >= off) incl += o;
        }
        if (lane == 63) wpart[wv] = incl;
        __syncthreads();
        unsigned wbase = 0;
        for (int i2 = 0; i2 < wv; i2++) wbase += wpart[i2];
        const unsigned exclT = wbase + incl - tsum;
        const int need = KSEL - S;
        if ((int)exclT < need && need <= (int)(exclT + tsum)) {
            unsigned cum = exclT;
            for (int i2 = 0; i2 < bpt; i2++) {
                unsigned h = hv[i2];
                if ((int)cum < need && need <= (int)(cum + h)) {
                    unsigned Bbin = (unsigned)(t*bpt + i2);
                    unsigned nP = (round == 0) ? Bbin : ((P << wb) | Bbin);
                    int Snew = S + (int)cum;
                    int tot  = Snew + (int)h;
                    sstate[0] = (int)nP; sstate[1] = Snew; sstate[2] = (int)h;
                    sstate[3] = (tot <= 64) ? 1 : ((round == 2) ? 2 : 0);
                    sstate[4] = 0;
                    break;
                }
                cum += h;
            }
        }
        __syncthreads();
        P = (unsigned)sstate[0]; S = sstate[1]; cntB = sstate[2]; mode = sstate[3];
        gsh = sh;
        if (mode) break;
    }

    int total;
    if (mode != 2) {
        // unordered block compaction (bitonic sort restores (key,idx) order)
        const unsigned long long lmask = (1ull << lane) - 1ull;
        #pragma unroll
        for (int it = 0; it < ITER; it++) {
            int j = t + 256*it;
            unsigned key = keys[j];
            bool f = ((key >> gsh) <= P);
            unsigned long long bal = __ballot(f);
            int wcnt = __popcll(bal);
            int base = 0;
            if (lane == 0 && wcnt) base = atomicAdd((unsigned*)&sstate[4], (unsigned)wcnt);
            base = __shfl(base, 0);
            if (f) {
                int pos = base + __popcll(bal & lmask);
                skey[pos] = key; sidx[pos] = (unsigned)j;
            }
        }
        total = S + cntB;
    } else {
        // exact float ties at the boundary: wave-0 serial, definite-ins then ties by index
        if (t < 64) {
            const unsigned long long lmask = (1ull << lane) - 1ull;
            int cnt = 0;
            for (int it = 0; it < NCAND/64; it++) {
                int j = lane + 64*it;
                unsigned key = keys[j];
                bool f = (key < P);
                unsigned long long bal = __ballot(f);
                if (f) { int pos = cnt + __popcll(bal & lmask); skey[pos] = key; sidx[pos] = (unsigned)j; }
                cnt += __popcll(bal);
            }
            for (int it = 0; it < NCAND/64; it++) {
                int j = lane + 64*it;
                unsigned key = keys[j];
                bool f = (key == P);
                unsigned long long bal = __ballot(f);
                if (f) {
                    int pos = cnt + __popcll(bal & lmask);
                    if (pos < 64) { skey[pos] = key; sidx[pos] = (unsigned)j; }
                }
                cnt += __popcll(bal);
            }
            if (lane == 0) sstate[5] = min(cnt, 64);
        }
        __syncthreads();
        total = sstate[5];
    }
    __syncthreads();

    // 64-lane bitonic sort on wave 0: (key, idx) ascending
    if (t < 64) {
        unsigned long long v = ~0ull;
        if (lane < total) v = (((unsigned long long)skey[lane]) << 32) | sidx[lane];
        #pragma unroll
        for (int k = 2; k <= 64; k <<= 1) {
            #pragma unroll
            for (int jj = k >> 1; jj > 0; jj >>= 1) {
                unsigned long long p = shfl_xor_u64(v, jj);
                bool up = ((lane & k) == 0);
                bool takeMin = (((lane & jj) == 0) == up);
                bool pl = p < v;
                v = (takeMin == pl) ? p : v;
            }
        }
        if (EPI == 0) {
            if (lane < KSEL)
                nidx[gp*KSEL + lane] = b*NCAND + (int)(v & 0xffffffffull);
        } else {
            float w = 0.f;
            if (lane < KSEL)
                w = 1.f / (__uint_as_float((unsigned)(v >> 32)) + 1e-8f);
            float ws = w;
            ws += __shfl_xor(ws, 1); ws += __shfl_xor(ws, 2); ws += __shfl_xor(ws, 4);
            if (lane < KSEL) {
                swt[lane]  = w / ws;
                sidx[lane] = (unsigned)(v & 0xffffffffull);
            }
        }
    }
    if (EPI == 1) {
        __syncthreads();
        if (t < DS) {
            const float* x2b = x2 + (size_t)b*NCAND*DS;
            float a = 0.f;
            #pragma unroll
            for (int r = 0; r < KSEL; r++)
                a = fmaf(swt[r], x2b[(size_t)sidx[r]*DS + t], a);
            xi[(size_t)gp*DS + t] = a;
        }
    }
}

// ---------------------------------------------------------------- launch
extern "C" void kernel_launch(void* const* d_in, const int* in_sizes, int n_in,
                              void* d_out, int out_size, void* d_ws, size_t ws_size,
                              hipStream_t stream)
{
    const float* p1 = (const float*)d_in[0];
    const float* x1 = (const float*)d_in[1];
    const int*   o1 = (const int*)d_in[2];
    const float* p2 = (const float*)d_in[3];
    const float* x2 = (const float*)d_in[4];
    const float* W_dense = (const float*)d_in[7];
    const float* b_dense = (const float*)d_in[8];
    const float* g_dense = (const float*)d_in[9];
    const float* bt_dense= (const float*)d_in[10];
    const float* Wq = (const float*)d_in[11];
    const float* Wk = (const float*)d_in[12];
    const float* Wv = (const float*)d_in[13];
    const float* W1 = (const float*)d_in[14];
    const float* b1 = (const float*)d_in[15];
    const float* g1 = (const float*)d_in[16];
    const float* bt1= (const float*)d_in[17];
    const float* W2 = (const float*)d_in[18];
    const float* W_out = (const float*)d_in[20];
    const float* b_out = (const float*)d_in[21];
    const float* g_out = (const float*)d_in[22];
    const float* bt_out= (const float*)d_in[23];

    float* ws   = (float*)d_ws;
    unsigned short* hpre = (unsigned short*)(ws + OFF_HPRE);
    unsigned short* wts  = (unsigned short*)(ws + OFF_WTS);
    float* tmp  = ws + OFF_TMP;
    float* xd   = ws + OFF_XD;
    float* xi   = ws + OFF_XI;
    float* qm   = ws + OFF_Q;
    float* km   = ws + OFF_K;
    float* vm   = ws + OFF_V;
    float* outp = ws + OFF_OUTP;
    int*   nidx = (int*)(ws + OFF_NIDX);
    float* stat = ws + OFF_STAT;
    float* sums_d = stat,      *sumsq_d = stat+256,  *scale_d = stat+512,  *shift_d = stat+768;
    float* sums_h = stat+1024, *sumsq_h = stat+1280, *scale_h = stat+1536, *shift_h = stat+1792;
    float* sums_o = stat+2048, *sumsq_o = stat+2304, *scale_o = stat+2560, *shift_o = stat+2816;
    float* out = (float*)d_out;

    hipMemsetAsync(stat, 0, 3*1024*sizeof(float), stream);
    k_copyout<<<(OUT_P1 + BB + 255)/256, 256, 0, stream>>>(p1, o1, out);

    // weight swizzles (hi/lo planes)
    k_swizzle_hl<<<16, 64, 0, stream>>>(W_dense, 128, wts+WDH, wts+WDL);
    k_swizzle_hl<<<32, 64, 0, stream>>>(Wq, 128, wts+WQH, wts+WQL);
    k_swizzle_hl<<<32, 64, 0, stream>>>(Wk, 128, wts+WKH, wts+WKL);
    k_swizzle_hl<<<32, 64, 0, stream>>>(Wv, 128, wts+WVH, wts+WVL);
    k_swizzle_hl<<<32, 64, 0, stream>>>(W1, 128, wts+W1H, wts+W1L);
    k_swizzle_hl<<<32, 64, 0, stream>>>(W2, 128, wts+W2H, wts+W2L);
    k_swizzle_hl<<<96, 64, 0, stream>>>(W_out, 256, wts+WOH, wts+WOL);

    // dense_mlp
    k_gemm_mf<128,64,0><<<M1/64, 256, 0, stream>>>(x1, wts+WDH, wts+WDL, b_dense, tmp, nullptr);
    k_colstats<<<128, 256, 0, stream>>>(tmp, M1, DS, sums_d, sumsq_d);
    k_finalize<<<1, 256, 0, stream>>>(sums_d, sumsq_d, g_dense, bt_dense, M1, DS, scale_d, shift_d);
    k_bnrelu<<<(M1*DS)/256, 256, 0, stream>>>(tmp, scale_d, shift_d, xd, (size_t)M1*DS, DS);

    // interpolation (cooperative radix select, K=8)
    k_sel<NN2, KI, 1><<<M1, 256, 0, stream>>>(p1, p2, nullptr, x2, xi);

    // q, k, v projections
    k_gemm_mf<128,128,0><<<M1/64, 256, 0, stream>>>(xd, wts+WQH, wts+WQL, nullptr, qm, nullptr);
    k_gemm_mf<128,128,0><<<M1/64, 256, 0, stream>>>(xi, wts+WKH, wts+WKL, nullptr, km, nullptr);
    k_gemm_mf<128,128,0><<<M1/64, 256, 0, stream>>>(xi, wts+WVH, wts+WVL, nullptr, vm, nullptr);

    // kNN-16 (cooperative radix select)
    k_sel<NN1, KN, 0><<<M1, 256, 0, stream>>>(p1, p1, nidx, nullptr, nullptr);

    // h-GEMM (MFMA, fused BN stats) -> hpre bf16
    k_gemm_h<<<MH/128, 256, 0, stream>>>(qm, km, xd, nidx, wts+W1H, b1, hpre, sums_h, sumsq_h);
    k_finalize<<<1, 256, 0, stream>>>(sums_h, sumsq_h, g1, bt1, MH, DS, scale_h, shift_h);

    // attn (MFMA)
    k_attn2<<<M1/4, 256, 0, stream>>>(hpre, scale_h, shift_h, wts+W2H, vm, xd, nidx, tmp);

    // output mlp
    k_gemm_mf<256,192,2><<<M1/64, 256, 0, stream>>>(tmp, wts+WOH, wts+WOL, b_out, outp, x1);
    k_colstats<<<128, 256, 0, stream>>>(outp, M1, DOUT, sums_o, sumsq_o);
    k_finalize<<<1, 256, 0, stream>>>(sums_o, sumsq_o, g_out, bt_out, M1, DOUT, scale_o, shift_o);
    k_bnrelu<<<(M1*DOUT)/256, 256, 0, stream>>>(outp, scale_o, shift_o, out + OUT_X,
        (size_t)M1*DOUT, DOUT);
}

// Round 6
// 489.733 us; speedup vs baseline: 1.3951x; 1.1715x over previous
//
#include <hip/hip_runtime.h>
#include <math.h>

#define BB 4
#define NN1 4096
#define NN2 1024
#define DS 128
#define DD 64
#define DOUT 256
#define M1 16384        // BB*NN1
#define MH 262144       // M1*16
#define KCAT 192        // DS+DD
#define KI 8            // interp k
#define KN 16           // neighbor k

#define OUT_P1 49152
#define OUT_X  49152
#define OUT_O1 4243456

// ---- workspace layout (float offsets) ----
static const size_t OFF_HPRE = 0;                      // bf16 MH*DS
static const size_t OFF_WTS  = 16777216;               // swizzled weights (hi/lo)
static const size_t OFF_TMP  = 33554432;
static const size_t OFF_XD   = OFF_TMP  + 2097152;
static const size_t OFF_XI   = OFF_XD   + 2097152;
static const size_t OFF_Q    = OFF_XI   + 2097152;
static const size_t OFF_K    = OFF_Q    + 2097152;
static const size_t OFF_V    = OFF_K    + 2097152;
static const size_t OFF_OUTP = OFF_V    + 2097152;
static const size_t OFF_NIDX = OFF_OUTP + 4194304;
static const size_t OFF_STAT = OFF_NIDX + 262144;

// ushort offsets inside the weights region
#define WDH 0
#define WDL 8192
#define WQH 16384
#define WQL 32768
#define WKH 49152
#define WKL 65536
#define WVH 81920
#define WVL 98304
#define W1H 114688
#define W1L 131072
#define W2H 147456
#define W2L 163840
#define WOH 180224
#define WOL 229376

typedef __attribute__((ext_vector_type(8))) short short8;
typedef __attribute__((ext_vector_type(4))) float floatx4;

__device__ inline unsigned short f2bf(float f) {
    union { float f; unsigned int u; } x; x.f = f;
    unsigned int r = x.u + 0x7fffu + ((x.u >> 16) & 1u);
    return (unsigned short)(r >> 16);
}
__device__ inline float bf2f(unsigned short h) {
    union { unsigned int u; float f; } x; x.u = ((unsigned int)h) << 16;
    return x.f;
}
__device__ inline unsigned long long shfl_xor_u64(unsigned long long v, int m) {
    unsigned lo = (unsigned)v, hi = (unsigned)(v >> 32);
    lo = (unsigned)__shfl_xor((int)lo, m);
    hi = (unsigned)__shfl_xor((int)hi, m);
    return ((unsigned long long)hi << 32) | lo;
}

// ---------------------------------------------------------------- copy p1/o1
__global__ void k_copyout(const float* __restrict__ p1, const int* __restrict__ o1,
                          float* __restrict__ out)
{
    int i = blockIdx.x * 256 + threadIdx.x;
    if (i < OUT_P1) out[i] = p1[i];
    else if (i < OUT_P1 + BB) out[OUT_O1 + (i - OUT_P1)] = (float)o1[i - OUT_P1];
}

// --------------------------- fused W swizzle (all 7 weights), hi+lo planes
struct SwzParams {
    const float* W[7];
    unsigned short* hi[7];
    unsigned short* lo[7];
    int N[7];
    int fid0[8];
};
__global__ __launch_bounds__(64) void k_swizzle_all(SwzParams p)
{
    int blk = blockIdx.x, lane = threadIdx.x;
    int seg = 0;
    #pragma unroll
    for (int i = 1; i < 7; i++) if (blk >= p.fid0[i]) seg = i;
    int fid = blk - p.fid0[seg];
    const float* W = p.W[seg];
    int N = p.N[seg];
    int ncj = N >> 4;
    int slab = fid / ncj, cj = fid - slab*ncj;
    int n  = cj*16 + (lane & 15);
    int k0 = slab*32 + (lane >> 4)*8;
    unsigned int oh[8], ol[8];
    #pragma unroll
    for (int j = 0; j < 8; j++) {
        float v = W[(size_t)(k0 + j) * N + n];
        unsigned short h = f2bf(v);
        oh[j] = h;
        ol[j] = f2bf(v - bf2f(h));
    }
    uint4 ph, pl;
    ph.x = oh[0] | (oh[1] << 16); ph.y = oh[2] | (oh[3] << 16);
    ph.z = oh[4] | (oh[5] << 16); ph.w = oh[6] | (oh[7] << 16);
    pl.x = ol[0] | (ol[1] << 16); pl.y = ol[2] | (ol[3] << 16);
    pl.z = ol[4] | (ol[5] << 16); pl.w = ol[6] | (ol[7] << 16);
    ((uint4*)p.hi[seg])[fid*64 + lane] = ph;
    ((uint4*)p.lo[seg])[fid*64 + lane] = pl;
}

// ----------------------------- split-bf16 MFMA GEMM (near-fp32 via hi/lo x 3)
// mode 0: A plain (stride K). mode 2: A = concat(Amat[.,0:128], aux[.,0:64])
// STATS: fuse BN column sums/sumsq (post-bias) via LDS + global atomics
template<int N, int K, int MODE, int STATS>
__global__ __launch_bounds__(256) void k_gemm_mf(
    const float* __restrict__ Amat, const unsigned short* __restrict__ Whi,
    const unsigned short* __restrict__ Wlo, const float* __restrict__ bias,
    float* __restrict__ C, const float* __restrict__ aux,
    float* __restrict__ sums, float* __restrict__ sumsq)
{
    __shared__ float sstat[STATS ? 2*N : 1];
    const int t = threadIdx.x, w = t >> 6, lane = t & 63;
    const int quad = lane >> 4, c = lane & 15;
    const int row = blockIdx.x*64 + w*16 + c;
    const int sA = (MODE == 2) ? DS : K;
    constexpr int nslab = K >> 5;
    constexpr int ncj = N >> 4;
    if (STATS) {
        for (int i = t; i < 2*N; i += 256) sstat[i] = 0.f;
        __syncthreads();
    }
    floatx4 acc[ncj];
    #pragma unroll
    for (int cj = 0; cj < ncj; cj++) acc[cj] = (floatx4){0.f,0.f,0.f,0.f};

    #pragma unroll
    for (int slab = 0; slab < nslab; slab++) {
        const int kk = slab*32 + quad*8;
        const float* src;
        if (MODE == 2 && kk >= DS) src = aux + (size_t)row*DD + (kk - DS);
        else                       src = Amat + (size_t)row*sA + kk;
        floatx4 va = *(const floatx4*)src;
        floatx4 vb = *(const floatx4*)(src + 4);
        short8 ahi, alo;
        #pragma unroll
        for (int j = 0; j < 4; j++) {
            unsigned short h = f2bf(va[j]);
            ahi[j] = (short)h; alo[j] = (short)f2bf(va[j] - bf2f(h));
        }
        #pragma unroll
        for (int j = 0; j < 4; j++) {
            unsigned short h = f2bf(vb[j]);
            ahi[4+j] = (short)h; alo[4+j] = (short)f2bf(vb[j] - bf2f(h));
        }
        const short8* bh = (const short8*)Whi + (size_t)slab*ncj*64;
        const short8* bl = (const short8*)Wlo + (size_t)slab*ncj*64;
        #pragma unroll
        for (int cj = 0; cj < ncj; cj++) {
            short8 bhv = bh[cj*64 + lane];
            short8 blv = bl[cj*64 + lane];
            acc[cj] = __builtin_amdgcn_mfma_f32_16x16x32_bf16(alo, bhv, acc[cj], 0, 0, 0);
            acc[cj] = __builtin_amdgcn_mfma_f32_16x16x32_bf16(ahi, blv, acc[cj], 0, 0, 0);
            acc[cj] = __builtin_amdgcn_mfma_f32_16x16x32_bf16(ahi, bhv, acc[cj], 0, 0, 0);
        }
    }
    const int rbase = blockIdx.x*64 + w*16 + quad*4;
    #pragma unroll
    for (int cj = 0; cj < ncj; cj++) {
        const float bb = bias ? bias[cj*16 + c] : 0.f;
        float s = 0.f, ss = 0.f;
        #pragma unroll
        for (int p = 0; p < 4; p++) {
            float v = acc[cj][p] + bb;
            C[(size_t)(rbase + p)*N + cj*16 + c] = v;
            if (STATS) { s += v; ss += v*v; }
        }
        if (STATS) {
            s  += __shfl_xor(s, 16);  s  += __shfl_xor(s, 32);
            ss += __shfl_xor(ss, 16); ss += __shfl_xor(ss, 32);
            if (quad == 0) {
                atomicAdd(&sstat[cj*16 + c], s);
                atomicAdd(&sstat[N + cj*16 + c], ss);
            }
        }
    }
    if (STATS) {
        __syncthreads();
        for (int i = t; i < N; i += 256) {
            atomicAdd(&sums[i],  sstat[i]);
            atomicAdd(&sumsq[i], sstat[N + i]);
        }
    }
}

// ------------------------------------------- MFMA h-GEMM + fused BN stats
__global__ __launch_bounds__(256) void k_gemm_h(
    const float* __restrict__ q, const float* __restrict__ km,
    const float* __restrict__ xe, const int* __restrict__ nidx,
    const unsigned short* __restrict__ W1sw, const float* __restrict__ b1,
    unsigned short* __restrict__ hpre,
    float* __restrict__ sums, float* __restrict__ sumsq)
{
    __shared__ unsigned short WF[16384];
    __shared__ unsigned short outT[128*128];
    __shared__ float sstat[256];
    const int t = threadIdx.x;
    const int w = t >> 6, lane = t & 63;
    sstat[t] = 0.f;
    #pragma unroll
    for (int i = 0; i < 8; i++)
        ((uint4*)WF)[t + 256*i] = ((const uint4*)W1sw)[t + 256*i];
    __syncthreads();

    const int quad = lane >> 4, c = lane & 15;
    const int r0 = blockIdx.x * 128 + w * 32;
    const int nid0 = nidx[r0 + c];
    const int nid1 = nidx[r0 + 16 + c];
    const int pr0 = r0 >> 4;
    const int pr1 = pr0 + 1;

    floatx4 acc[2][8];
    #pragma unroll
    for (int ti = 0; ti < 2; ti++)
        #pragma unroll
        for (int cj = 0; cj < 8; cj++)
            acc[ti][cj] = (floatx4){0.f, 0.f, 0.f, 0.f};

    for (int ks = 0; ks < 4; ks++) {
        short8 bf[8];
        #pragma unroll
        for (int cj = 0; cj < 8; cj++)
            bf[cj] = ((const short8*)WF)[(ks*8 + cj)*64 + lane];
        const int ko = ks*32 + quad*8;
        #pragma unroll
        for (int ti = 0; ti < 2; ti++) {
            const int pr = ti ? pr1 : pr0;
            const int m  = ti ? nid1 : nid0;
            const float* qp = q  + (size_t)pr*DS + ko;
            const float* kp = km + (size_t)m*DS + ko;
            const float* xp = xe + (size_t)m*DS + ko;
            floatx4 qa = *(const floatx4*)qp,       qb = *(const floatx4*)(qp+4);
            floatx4 ka = *(const floatx4*)kp,       kb = *(const floatx4*)(kp+4);
            floatx4 xa = *(const floatx4*)xp,       xb = *(const floatx4*)(xp+4);
            short8 af;
            #pragma unroll
            for (int j = 0; j < 4; j++) af[j]   = (short)f2bf(qa[j] - ka[j] + xa[j]);
            #pragma unroll
            for (int j = 0; j < 4; j++) af[4+j] = (short)f2bf(qb[j] - kb[j] + xb[j]);
            #pragma unroll
            for (int cj = 0; cj < 8; cj++)
                acc[ti][cj] = __builtin_amdgcn_mfma_f32_16x16x32_bf16(af, bf[cj], acc[ti][cj], 0, 0, 0);
        }
    }

    #pragma unroll
    for (int cj = 0; cj < 8; cj++) {
        const float bb = b1[cj*16 + c];
        float s = 0.f, ss = 0.f;
        #pragma unroll
        for (int ti = 0; ti < 2; ti++)
            #pragma unroll
            for (int p = 0; p < 4; p++) {
                float v = acc[ti][cj][p] + bb;
                s += v; ss += v*v;
                int lr = w*32 + ti*16 + quad*4 + p;
                outT[lr*128 + cj*16 + c] = f2bf(v);
            }
        s  += __shfl_xor(s, 16);  s  += __shfl_xor(s, 32);
        ss += __shfl_xor(ss, 16); ss += __shfl_xor(ss, 32);
        if (quad == 0) {
            atomicAdd(&sstat[cj*16 + c], s);
            atomicAdd(&sstat[128 + cj*16 + c], ss);
        }
    }
    __syncthreads();
    unsigned short* gdst = hpre + (size_t)blockIdx.x * 128 * 128;
    #pragma unroll
    for (int i = 0; i < 8; i++)
        ((uint4*)gdst)[t + 256*i] = ((const uint4*)outT)[t + 256*i];
    if (t < 128) atomicAdd(&sums[t], sstat[t]);
    else         atomicAdd(&sumsq[t - 128], sstat[t]);
}

// ---------------------------- MFMA attn: bn+relu -> sim GEMM -> softmax -> agg
__global__ __launch_bounds__(256) void k_attn2(
    const unsigned short* __restrict__ hpre, const float* __restrict__ scale_h,
    const float* __restrict__ shift_h, const unsigned short* __restrict__ W2sw,
    const float* __restrict__ v, const float* __restrict__ xe,
    const int* __restrict__ nidx, float* __restrict__ agg)
{
    __shared__ unsigned short WF[16384];
    const int t = threadIdx.x;
    #pragma unroll
    for (int i = 0; i < 8; i++)
        ((uint4*)WF)[t + 256*i] = ((const uint4*)W2sw)[t + 256*i];
    __syncthreads();

    const int w = t >> 6, lane = t & 63;
    const int gp = blockIdx.x * 4 + w;
    const int quad = lane >> 4, c = lane & 15;

    floatx4 acc[8];
    #pragma unroll
    for (int cj = 0; cj < 8; cj++) acc[cj] = (floatx4){0.f, 0.f, 0.f, 0.f};

    for (int ks = 0; ks < 4; ks++) {
        const int ko = ks*32 + quad*8;
        const unsigned short* hp = hpre + ((size_t)gp*16 + c)*DS + ko;
        uint4 hv = *(const uint4*)hp;
        floatx4 sc0 = *(const floatx4*)(scale_h + ko);
        floatx4 sc1 = *(const floatx4*)(scale_h + ko + 4);
        floatx4 sh0 = *(const floatx4*)(shift_h + ko);
        floatx4 sh1 = *(const floatx4*)(shift_h + ko + 4);
        unsigned int hw[4] = {hv.x, hv.y, hv.z, hv.w};
        short8 af;
        #pragma unroll
        for (int j = 0; j < 4; j++) {
            unsigned short u0 = (unsigned short)(hw[j] & 0xffffu);
            unsigned short u1 = (unsigned short)(hw[j] >> 16);
            float f0 = fmaxf(fmaf(bf2f(u0), (j<2)?sc0[2*j]:sc1[2*j-4],   (j<2)?sh0[2*j]:sh1[2*j-4]),   0.f);
            float f1 = fmaxf(fmaf(bf2f(u1), (j<2)?sc0[2*j+1]:sc1[2*j-3], (j<2)?sh0[2*j+1]:sh1[2*j-3]), 0.f);
            af[2*j]   = (short)f2bf(f0);
            af[2*j+1] = (short)f2bf(f1);
        }
        #pragma unroll
        for (int cj = 0; cj < 8; cj++) {
            short8 bfv = ((const short8*)WF)[(ks*8 + cj)*64 + lane];
            acc[cj] = __builtin_amdgcn_mfma_f32_16x16x32_bf16(af, bfv, acc[cj], 0, 0, 0);
        }
    }

    int nid[4];
    #pragma unroll
    for (int p = 0; p < 4; p++) nid[p] = nidx[gp*16 + quad*4 + p];

    #pragma unroll
    for (int cj = 0; cj < 8; cj++) {
        float m4 = fmaxf(fmaxf(acc[cj][0], acc[cj][1]), fmaxf(acc[cj][2], acc[cj][3]));
        m4 = fmaxf(m4, __shfl_xor(m4, 16));
        m4 = fmaxf(m4, __shfl_xor(m4, 32));
        float e[4]; float s4 = 0.f;
        #pragma unroll
        for (int p = 0; p < 4; p++) { e[p] = __expf(acc[cj][p] - m4); s4 += e[p]; }
        s4 += __shfl_xor(s4, 16); s4 += __shfl_xor(s4, 32);
        const float inv = 1.f / s4;
        const int col = cj*16 + c;
        float a = 0.f;
        #pragma unroll
        for (int p = 0; p < 4; p++) {
            const int m = nid[p];
            a = fmaf(e[p]*inv, v[(size_t)m*DS + col] + xe[(size_t)m*DS + col], a);
        }
        a += __shfl_xor(a, 16); a += __shfl_xor(a, 32);
        if (quad == 0) agg[(size_t)gp*DS + col] = a;
    }
}

__global__ void k_finalize(const float* __restrict__ sums, const float* __restrict__ sumsq,
                           const float* __restrict__ g, const float* __restrict__ bt,
                           int M, int N, float* __restrict__ scale, float* __restrict__ shift)
{
    int c = blockIdx.x * blockDim.x + threadIdx.x;
    if (c < N) {
        float m  = sums[c] / (float)M;
        float var = sumsq[c] / (float)M - m*m;
        float sc = g[c] * rsqrtf(var + 1e-5f);
        scale[c] = sc;
        shift[c] = bt[c] - m * sc;
    }
}

__global__ __launch_bounds__(256) void k_bnrelu(
    const float* __restrict__ X, const float* __restrict__ scale,
    const float* __restrict__ shift, float* __restrict__ Y, size_t total, int N)
{
    size_t i = (size_t)blockIdx.x * 256 + threadIdx.x;
    if (i < total) {
        int c = (int)(i & (size_t)(N - 1));
        Y[i] = fmaxf(fmaf(X[i], scale[c], shift[c]), 0.f);
    }
}

// --------------- cooperative radix-select top-K, keys in VGPRs, 16KB LDS hist
// rounds on float-d bits: [31:20] (4096 bins), [19:8] (4096), [7:0] (256)
// EPI 0: write nidx (K=16).  EPI 1: inverse-distance interp (K=8) -> xi.
template<int NCAND, int KSEL, int EPI>
__global__ __launch_bounds__(256) void k_sel(
    const float* __restrict__ qpts, const float* __restrict__ cpts,
    int* __restrict__ nidx, const float* __restrict__ x2, float* __restrict__ xi)
{
    __shared__ unsigned hist[4096];
    __shared__ unsigned skey[64];
    __shared__ unsigned sidx[64];
    __shared__ float    swt[KSEL];
    __shared__ unsigned wpart[4];
    __shared__ int      sstate[8];   // P,S,cntB,mode,compact-counter,fb-total

    const int gp = blockIdx.x, b = gp >> 12;
    const int t = threadIdx.x, wv = t >> 6, lane = t & 63;
    constexpr int ITER = NCAND / 256;

    const float px = qpts[gp*3+0], py = qpts[gp*3+1], pz = qpts[gp*3+2];
    const float sa = px*px + py*py + pz*pz;
    const float* pb = cpts + (size_t)b*NCAND*3;

    unsigned kreg[ITER];
    #pragma unroll
    for (int it = 0; it < ITER; it++) {
        int j = t + 256*it;
        float qx = pb[j*3+0], qy = pb[j*3+1], qz = pb[j*3+2];
        float sb  = qx*qx + qy*qy + qz*qz;
        float dot = px*qx + py*qy + pz*qz;
        float d = sqrtf(fmaxf((sa + sb) - 2.f*dot, 0.f));
        kreg[it] = __float_as_uint(d);
    }

    unsigned P = 0;
    int S = 0, cntB = 0, mode = 0, gsh = 0;
    for (int round = 0; round < 3; round++) {
        const int nb  = (round < 2) ? 4096 : 256;
        const int bpt = nb >> 8;
        const int wb  = (round < 2) ? 12 : 8;
        const int sh  = (round == 0) ? 20 : (round == 1 ? 8 : 0);
        const int psh = (sh + wb) & 31;
        for (int i2 = t; i2 < (nb >> 2); i2 += 256)
            ((uint4*)hist)[i2] = (uint4){0u,0u,0u,0u};
        __syncthreads();
        #pragma unroll
        for (int it = 0; it < ITER; it++) {
            unsigned key = kreg[it];
            bool act = (round == 0) ? true : ((key >> psh) == P);
            if (act) atomicAdd(&hist[(key >> sh) & (nb - 1)], 1u);
        }
        __syncthreads();
        unsigned hv[16]; unsigned tsum = 0;
        if (bpt == 16) {
            #pragma unroll
            for (int qq = 0; qq < 4; qq++) {
                uint4 h4 = ((const uint4*)hist)[t*4 + qq];
                hv[qq*4+0]=h4.x; hv[qq*4+1]=h4.y; hv[qq*4+2]=h4.z; hv[qq*4+3]=h4.w;
            }
            #pragma unroll
            for (int qq = 0; qq < 16; qq++) tsum += hv[qq];
        } else {
            hv[0] = hist[t]; tsum = hv[0];
        }
        unsigned incl = tsum;
        #pragma unroll
        for (int off = 1; off < 64; off <<= 1) {
            unsigned o = (unsigned)__shfl_up((int)incl, off);
            if (lane >= off) incl += o;
        }
        if (lane == 63) wpart[wv] = incl;
        __syncthreads();
        unsigned wbase = 0;
        for (int i2 = 0; i2 < wv; i2++) wbase += wpart[i2];
        const unsigned exclT = wbase + incl - tsum;
        const int need = KSEL - S;
        if ((int)exclT < need && need <= (int)(exclT + tsum)) {
            unsigned cum = exclT;
            for (int i2 = 0; i2 < bpt; i2++) {
                unsigned h = hv[i2];
                if ((int)cum < need && need <= (int)(cum + h)) {
                    unsigned Bbin = (unsigned)(t*bpt + i2);
                    unsigned nP = (round == 0) ? Bbin : ((P << wb) | Bbin);
                    int Snew = S + (int)cum;
                    int tot  = Snew + (int)h;
                    sstate[0] = (int)nP; sstate[1] = Snew; sstate[2] = (int)h;
                    sstate[3] = (tot <= 64) ? 1 : ((round == 2) ? 2 : 0);
                    sstate[4] = 0;
                    break;
                }
                cum += h;
            }
        }
        __syncthreads();
        P = (unsigned)sstate[0]; S = sstate[1]; cntB = sstate[2]; mode = sstate[3];
        gsh = sh;
        if (mode) break;
    }

    int total;
    if (mode != 2) {
        // unordered block compaction (bitonic sort restores (key,idx) order)
        const unsigned long long lmask = (1ull << lane) - 1ull;
        #pragma unroll
        for (int it = 0; it < ITER; it++) {
            int j = t + 256*it;
            unsigned key = kreg[it];
            bool f = ((key >> gsh) <= P);
            unsigned long long bal = __ballot(f);
            int wcnt = __popcll(bal);
            int base = 0;
            if (lane == 0 && wcnt) base = atomicAdd((unsigned*)&sstate[4], (unsigned)wcnt);
            base = __shfl(base, 0);
            if (f) {
                int pos = base + __popcll(bal & lmask);
                skey[pos] = key; sidx[pos] = (unsigned)j;
            }
        }
        total = S + cntB;
    } else {
        // exact 32-bit tie overflow (rare): wave-0 serial recompute, ties by index
        if (t < 64) {
            const unsigned long long lmask = (1ull << lane) - 1ull;
            int cnt = 0;
            for (int pass = 0; pass < 2; pass++) {
                for (int it = 0; it < NCAND/64; it++) {
                    int j = lane + 64*it;
                    float qx = pb[j*3+0], qy = pb[j*3+1], qz = pb[j*3+2];
                    float sb  = qx*qx + qy*qy + qz*qz;
                    float dot = px*qx + py*qy + pz*qz;
                    unsigned key = __float_as_uint(sqrtf(fmaxf((sa + sb) - 2.f*dot, 0.f)));
                    bool f = pass ? (key == P) : (key < P);
                    unsigned long long bal = __ballot(f);
                    if (f) {
                        int pos = cnt + __popcll(bal & lmask);
                        if (pos < 64) { skey[pos] = key; sidx[pos] = (unsigned)j; }
                    }
                    cnt += __popcll(bal);
                }
            }
            if (lane == 0) sstate[5] = min(cnt, 64);
        }
        __syncthreads();
        total = sstate[5];
    }
    __syncthreads();

    // 64-lane bitonic sort on wave 0: (key, idx) ascending
    if (t < 64) {
        unsigned long long v = ~0ull;
        if (lane < total) v = (((unsigned long long)skey[lane]) << 32) | sidx[lane];
        #pragma unroll
        for (int k = 2; k <= 64; k <<= 1) {
            #pragma unroll
            for (int jj = k >> 1; jj > 0; jj >>= 1) {
                unsigned long long p = shfl_xor_u64(v, jj);
                bool up = ((lane & k) == 0);
                bool takeMin = (((lane & jj) == 0) == up);
                bool pl = p < v;
                v = (takeMin == pl) ? p : v;
            }
        }
        if (EPI == 0) {
            if (lane < KSEL)
                nidx[gp*KSEL + lane] = b*NCAND + (int)(v & 0xffffffffull);
        } else {
            float w = 0.f;
            if (lane < KSEL)
                w = 1.f / (__uint_as_float((unsigned)(v >> 32)) + 1e-8f);
            float ws = w;
            ws += __shfl_xor(ws, 1); ws += __shfl_xor(ws, 2); ws += __shfl_xor(ws, 4);
            if (lane < KSEL) {
                swt[lane]  = w / ws;
                sidx[lane] = (unsigned)(v & 0xffffffffull);
            }
        }
    }
    if (EPI == 1) {
        __syncthreads();
        if (t < DS) {
            const float* x2b = x2 + (size_t)b*NCAND*DS;
            float a = 0.f;
            #pragma unroll
            for (int r = 0; r < KSEL; r++)
                a = fmaf(swt[r], x2b[(size_t)sidx[r]*DS + t], a);
            xi[(size_t)gp*DS + t] = a;
        }
    }
}

// ---------------------------------------------------------------- launch
extern "C" void kernel_launch(void* const* d_in, const int* in_sizes, int n_in,
                              void* d_out, int out_size, void* d_ws, size_t ws_size,
                              hipStream_t stream)
{
    const float* p1 = (const float*)d_in[0];
    const float* x1 = (const float*)d_in[1];
    const int*   o1 = (const int*)d_in[2];
    const float* p2 = (const float*)d_in[3];
    const float* x2 = (const float*)d_in[4];
    const float* W_dense = (const float*)d_in[7];
    const float* b_dense = (const float*)d_in[8];
    const float* g_dense = (const float*)d_in[9];
    const float* bt_dense= (const float*)d_in[10];
    const float* Wq = (const float*)d_in[11];
    const float* Wk = (const float*)d_in[12];
    const float* Wv = (const float*)d_in[13];
    const float* W1 = (const float*)d_in[14];
    const float* b1 = (const float*)d_in[15];
    const float* g1 = (const float*)d_in[16];
    const float* bt1= (const float*)d_in[17];
    const float* W2 = (const float*)d_in[18];
    const float* W_out = (const float*)d_in[20];
    const float* b_out = (const float*)d_in[21];
    const float* g_out = (const float*)d_in[22];
    const float* bt_out= (const float*)d_in[23];

    float* ws   = (float*)d_ws;
    unsigned short* hpre = (unsigned short*)(ws + OFF_HPRE);
    unsigned short* wts  = (unsigned short*)(ws + OFF_WTS);
    float* tmp  = ws + OFF_TMP;
    float* xd   = ws + OFF_XD;
    float* xi   = ws + OFF_XI;
    float* qm   = ws + OFF_Q;
    float* km   = ws + OFF_K;
    float* vm   = ws + OFF_V;
    float* outp = ws + OFF_OUTP;
    int*   nidx = (int*)(ws + OFF_NIDX);
    float* stat = ws + OFF_STAT;
    float* sums_d = stat,      *sumsq_d = stat+256,  *scale_d = stat+512,  *shift_d = stat+768;
    float* sums_h = stat+1024, *sumsq_h = stat+1280, *scale_h = stat+1536, *shift_h = stat+1792;
    float* sums_o = stat+2048, *sumsq_o = stat+2304, *scale_o = stat+2560, *shift_o = stat+2816;
    float* out = (float*)d_out;

    hipMemsetAsync(stat, 0, 3*1024*sizeof(float), stream);
    k_copyout<<<(OUT_P1 + BB + 255)/256, 256, 0, stream>>>(p1, o1, out);

    // fused weight swizzles (hi/lo planes), 272 blocks total
    SwzParams sp;
    sp.W[0]=W_dense; sp.W[1]=Wq; sp.W[2]=Wk; sp.W[3]=Wv; sp.W[4]=W1; sp.W[5]=W2; sp.W[6]=W_out;
    sp.hi[0]=wts+WDH; sp.hi[1]=wts+WQH; sp.hi[2]=wts+WKH; sp.hi[3]=wts+WVH;
    sp.hi[4]=wts+W1H; sp.hi[5]=wts+W2H; sp.hi[6]=wts+WOH;
    sp.lo[0]=wts+WDL; sp.lo[1]=wts+WQL; sp.lo[2]=wts+WKL; sp.lo[3]=wts+WVL;
    sp.lo[4]=wts+W1L; sp.lo[5]=wts+W2L; sp.lo[6]=wts+WOL;
    sp.N[0]=128; sp.N[1]=128; sp.N[2]=128; sp.N[3]=128; sp.N[4]=128; sp.N[5]=128; sp.N[6]=256;
    sp.fid0[0]=0; sp.fid0[1]=16; sp.fid0[2]=48; sp.fid0[3]=80; sp.fid0[4]=112;
    sp.fid0[5]=144; sp.fid0[6]=176; sp.fid0[7]=272;
    k_swizzle_all<<<272, 64, 0, stream>>>(sp);

    // dense_mlp (stats fused)
    k_gemm_mf<128,64,0,1><<<M1/64, 256, 0, stream>>>(x1, wts+WDH, wts+WDL, b_dense, tmp,
        nullptr, sums_d, sumsq_d);
    k_finalize<<<1, 256, 0, stream>>>(sums_d, sumsq_d, g_dense, bt_dense, M1, DS, scale_d, shift_d);
    k_bnrelu<<<(M1*DS)/256, 256, 0, stream>>>(tmp, scale_d, shift_d, xd, (size_t)M1*DS, DS);

    // interpolation (cooperative radix select, K=8)
    k_sel<NN2, KI, 1><<<M1, 256, 0, stream>>>(p1, p2, nullptr, x2, xi);

    // q, k, v projections
    k_gemm_mf<128,128,0,0><<<M1/64, 256, 0, stream>>>(xd, wts+WQH, wts+WQL, nullptr, qm,
        nullptr, nullptr, nullptr);
    k_gemm_mf<128,128,0,0><<<M1/64, 256, 0, stream>>>(xi, wts+WKH, wts+WKL, nullptr, km,
        nullptr, nullptr, nullptr);
    k_gemm_mf<128,128,0,0><<<M1/64, 256, 0, stream>>>(xi, wts+WVH, wts+WVL, nullptr, vm,
        nullptr, nullptr, nullptr);

    // kNN-16 (cooperative radix select)
    k_sel<NN1, KN, 0><<<M1, 256, 0, stream>>>(p1, p1, nidx, nullptr, nullptr);

    // h-GEMM (MFMA, fused BN stats) -> hpre bf16
    k_gemm_h<<<MH/128, 256, 0, stream>>>(qm, km, xd, nidx, wts+W1H, b1, hpre, sums_h, sumsq_h);
    k_finalize<<<1, 256, 0, stream>>>(sums_h, sumsq_h, g1, bt1, MH, DS, scale_h, shift_h);

    // attn (MFMA)
    k_attn2<<<M1/4, 256, 0, stream>>>(hpre, scale_h, shift_h, wts+W2H, vm, xd, nidx, tmp);

    // output mlp (stats fused)
    k_gemm_mf<256,192,2,1><<<M1/64, 256, 0, stream>>>(tmp, wts+WOH, wts+WOL, b_out, outp,
        x1, sums_o, sumsq_o);
    k_finalize<<<1, 256, 0, stream>>>(sums_o, sumsq_o, g_out, bt_out, M1, DOUT, scale_o, shift_o);
    k_bnrelu<<<(M1*DOUT)/256, 256, 0, stream>>>(outp, scale_o, shift_o, out + OUT_X,
        (size_t)M1*DOUT, DOUT);
}

// Round 7
// 460.718 us; speedup vs baseline: 1.4830x; 1.0630x over previous
//
#include <hip/hip_runtime.h>
#include <math.h>

#define BB 4
#define NN1 4096
#define NN2 1024
#define DS 128
#define DD 64
#define DOUT 256
#define M1 16384        // BB*NN1
#define MH 262144       // M1*16
#define KCAT 192        // DS+DD
#define KI 8            // interp k
#define KN 16           // neighbor k

#define OUT_P1 49152
#define OUT_X  49152
#define OUT_O1 4243456

// ---- workspace layout (float offsets) ----
static const size_t OFF_HPRE = 0;                      // bf16 MH*DS
static const size_t OFF_WTS  = 16777216;               // swizzled weights (hi/lo)
static const size_t OFF_TMP  = 33554432;
static const size_t OFF_XD   = OFF_TMP  + 2097152;
static const size_t OFF_XI   = OFF_XD   + 2097152;
static const size_t OFF_Q    = OFF_XI   + 2097152;
static const size_t OFF_K    = OFF_Q    + 2097152;
static const size_t OFF_V    = OFF_K    + 2097152;
static const size_t OFF_OUTP = OFF_V    + 2097152;
static const size_t OFF_NIDX = OFF_OUTP + 4194304;
static const size_t OFF_STAT = OFF_NIDX + 262144;      // 3072 floats
static const size_t OFF_P1Q  = OFF_STAT + 4096;        // 16384 float4
static const size_t OFF_P2Q  = OFF_P1Q  + 65536;       // 4096 float4

// ushort offsets inside the weights region
#define WDH 0
#define WDL 8192
#define WQH 16384
#define WQL 32768
#define WKH 49152
#define WKL 65536
#define WVH 81920
#define WVL 98304
#define W1H 114688
#define W1L 131072
#define W2H 147456
#define W2L 163840
#define WOH 180224
#define WOL 229376

typedef __attribute__((ext_vector_type(8))) short short8;
typedef __attribute__((ext_vector_type(4))) float floatx4;

__device__ inline unsigned short f2bf(float f) {
    union { float f; unsigned int u; } x; x.f = f;
    unsigned int r = x.u + 0x7fffu + ((x.u >> 16) & 1u);
    return (unsigned short)(r >> 16);
}
__device__ inline float bf2f(unsigned short h) {
    union { unsigned int u; float f; } x; x.u = ((unsigned int)h) << 16;
    return x.f;
}
__device__ inline unsigned long long shfl_xor_u64(unsigned long long v, int m) {
    unsigned lo = (unsigned)v, hi = (unsigned)(v >> 32);
    lo = (unsigned)__shfl_xor((int)lo, m);
    hi = (unsigned)__shfl_xor((int)hi, m);
    return ((unsigned long long)hi << 32) | lo;
}

// --------------- prolog: copy p1/o1 to out, zero stats, pack points as float4
#define PRO_STAT  (OUT_P1 + BB)          // 49156
#define PRO_PACK  (PRO_STAT + 3072)      // 52228
#define PRO_TOTAL (PRO_PACK + M1 + BB*NN2)
__global__ void k_prolog(const float* __restrict__ p1, const int* __restrict__ o1,
                         const float* __restrict__ p2, float* __restrict__ out,
                         float* __restrict__ stat, float4* __restrict__ p1q,
                         float4* __restrict__ p2q)
{
    int i = blockIdx.x * 256 + threadIdx.x;
    if (i < OUT_P1) out[i] = p1[i];
    else if (i < PRO_STAT) out[OUT_O1 + (i - OUT_P1)] = (float)o1[i - OUT_P1];
    else if (i < PRO_PACK) stat[i - PRO_STAT] = 0.f;
    else if (i < PRO_TOTAL) {
        int j = i - PRO_PACK;
        const float* src; float4* dst; int jj;
        if (j < M1) { src = p1; dst = p1q; jj = j; }
        else        { src = p2; dst = p2q; jj = j - M1; }
        float x = src[jj*3+0], y = src[jj*3+1], z = src[jj*3+2];
        float n = fmaf(z, z, fmaf(y, y, x*x));
        dst[jj] = make_float4(x, y, z, n);
    }
}

// --------------------------- fused W swizzle (all 7 weights), hi+lo planes
struct SwzParams {
    const float* W[7];
    unsigned short* hi[7];
    unsigned short* lo[7];
    int N[7];
    int fid0[8];
};
__global__ __launch_bounds__(64) void k_swizzle_all(SwzParams p)
{
    int blk = blockIdx.x, lane = threadIdx.x;
    int seg = 0;
    #pragma unroll
    for (int i = 1; i < 7; i++) if (blk >= p.fid0[i]) seg = i;
    int fid = blk - p.fid0[seg];
    const float* W = p.W[seg];
    int N = p.N[seg];
    int ncj = N >> 4;
    int slab = fid / ncj, cj = fid - slab*ncj;
    int n  = cj*16 + (lane & 15);
    int k0 = slab*32 + (lane >> 4)*8;
    unsigned int oh[8], ol[8];
    #pragma unroll
    for (int j = 0; j < 8; j++) {
        float v = W[(size_t)(k0 + j) * N + n];
        unsigned short h = f2bf(v);
        oh[j] = h;
        ol[j] = f2bf(v - bf2f(h));
    }
    uint4 ph, pl;
    ph.x = oh[0] | (oh[1] << 16); ph.y = oh[2] | (oh[3] << 16);
    ph.z = oh[4] | (oh[5] << 16); ph.w = oh[6] | (oh[7] << 16);
    pl.x = ol[0] | (ol[1] << 16); pl.y = ol[2] | (ol[3] << 16);
    pl.z = ol[4] | (ol[5] << 16); pl.w = ol[6] | (ol[7] << 16);
    ((uint4*)p.hi[seg])[fid*64 + lane] = ph;
    ((uint4*)p.lo[seg])[fid*64 + lane] = pl;
}

// ----------------------------- split-bf16 MFMA GEMM (near-fp32 via hi/lo x 3)
// mode 0: A plain (stride K). mode 2: A = concat(Amat, aux[.,0:64]).
// mode 3: qkv — blockIdx.y in {0,1,2}: A = (y==0?Amat:aux), W/C offset by y.
// STATS: fuse BN column sums/sumsq (post-bias) via LDS + global atomics
template<int N, int K, int MODE, int STATS>
__global__ __launch_bounds__(256) void k_gemm_mf(
    const float* __restrict__ Amat, const unsigned short* __restrict__ Whi,
    const unsigned short* __restrict__ Wlo, const float* __restrict__ bias,
    float* __restrict__ C, const float* __restrict__ aux,
    float* __restrict__ sums, float* __restrict__ sumsq)
{
    __shared__ float sstat[STATS ? 2*N : 1];
    const int t = threadIdx.x, w = t >> 6, lane = t & 63;
    const int quad = lane >> 4, c = lane & 15;
    const int row = blockIdx.x*64 + w*16 + c;
    const int sA = (MODE == 2) ? DS : K;
    constexpr int nslab = K >> 5;
    constexpr int ncj = N >> 4;
    const int seg = (MODE == 3) ? blockIdx.y : 0;
    const float* Abase = (MODE == 3 && seg > 0) ? aux : Amat;
    const unsigned short* WhiS = Whi + (size_t)seg*32768;
    const unsigned short* WloS = Wlo + (size_t)seg*32768;
    float* CS = C + (size_t)seg*2097152;
    if (STATS) {
        for (int i = t; i < 2*N; i += 256) sstat[i] = 0.f;
        __syncthreads();
    }
    floatx4 acc[ncj];
    #pragma unroll
    for (int cj = 0; cj < ncj; cj++) acc[cj] = (floatx4){0.f,0.f,0.f,0.f};

    #pragma unroll
    for (int slab = 0; slab < nslab; slab++) {
        const int kk = slab*32 + quad*8;
        const float* src;
        if (MODE == 2 && kk >= DS) src = aux + (size_t)row*DD + (kk - DS);
        else                       src = Abase + (size_t)row*sA + kk;
        floatx4 va = *(const floatx4*)src;
        floatx4 vb = *(const floatx4*)(src + 4);
        short8 ahi, alo;
        #pragma unroll
        for (int j = 0; j < 4; j++) {
            unsigned short h = f2bf(va[j]);
            ahi[j] = (short)h; alo[j] = (short)f2bf(va[j] - bf2f(h));
        }
        #pragma unroll
        for (int j = 0; j < 4; j++) {
            unsigned short h = f2bf(vb[j]);
            ahi[4+j] = (short)h; alo[4+j] = (short)f2bf(vb[j] - bf2f(h));
        }
        const short8* bh = (const short8*)WhiS + (size_t)slab*ncj*64;
        const short8* bl = (const short8*)WloS + (size_t)slab*ncj*64;
        #pragma unroll
        for (int cj = 0; cj < ncj; cj++) {
            short8 bhv = bh[cj*64 + lane];
            short8 blv = bl[cj*64 + lane];
            acc[cj] = __builtin_amdgcn_mfma_f32_16x16x32_bf16(alo, bhv, acc[cj], 0, 0, 0);
            acc[cj] = __builtin_amdgcn_mfma_f32_16x16x32_bf16(ahi, blv, acc[cj], 0, 0, 0);
            acc[cj] = __builtin_amdgcn_mfma_f32_16x16x32_bf16(ahi, bhv, acc[cj], 0, 0, 0);
        }
    }
    const int rbase = blockIdx.x*64 + w*16 + quad*4;
    #pragma unroll
    for (int cj = 0; cj < ncj; cj++) {
        const float bb = bias ? bias[cj*16 + c] : 0.f;
        float s = 0.f, ss = 0.f;
        #pragma unroll
        for (int p = 0; p < 4; p++) {
            float v = acc[cj][p] + bb;
            CS[(size_t)(rbase + p)*N + cj*16 + c] = v;
            if (STATS) { s += v; ss += v*v; }
        }
        if (STATS) {
            s  += __shfl_xor(s, 16);  s  += __shfl_xor(s, 32);
            ss += __shfl_xor(ss, 16); ss += __shfl_xor(ss, 32);
            if (quad == 0) {
                atomicAdd(&sstat[cj*16 + c], s);
                atomicAdd(&sstat[N + cj*16 + c], ss);
            }
        }
    }
    if (STATS) {
        __syncthreads();
        for (int i = t; i < N; i += 256) {
            atomicAdd(&sums[i],  sstat[i]);
            atomicAdd(&sumsq[i], sstat[N + i]);
        }
    }
}

// ------------------------------------------- MFMA h-GEMM + fused BN stats
__global__ __launch_bounds__(256) void k_gemm_h(
    const float* __restrict__ q, const float* __restrict__ km,
    const float* __restrict__ xe, const int* __restrict__ nidx,
    const unsigned short* __restrict__ W1sw, const float* __restrict__ b1,
    unsigned short* __restrict__ hpre,
    float* __restrict__ sums, float* __restrict__ sumsq)
{
    __shared__ unsigned short WF[16384];
    __shared__ unsigned short outT[128*128];
    __shared__ float sstat[256];
    const int t = threadIdx.x;
    const int w = t >> 6, lane = t & 63;
    sstat[t] = 0.f;
    #pragma unroll
    for (int i = 0; i < 8; i++)
        ((uint4*)WF)[t + 256*i] = ((const uint4*)W1sw)[t + 256*i];
    __syncthreads();

    const int quad = lane >> 4, c = lane & 15;
    const int r0 = blockIdx.x * 128 + w * 32;
    const int nid0 = nidx[r0 + c];
    const int nid1 = nidx[r0 + 16 + c];
    const int pr0 = r0 >> 4;
    const int pr1 = pr0 + 1;

    floatx4 acc[2][8];
    #pragma unroll
    for (int ti = 0; ti < 2; ti++)
        #pragma unroll
        for (int cj = 0; cj < 8; cj++)
            acc[ti][cj] = (floatx4){0.f, 0.f, 0.f, 0.f};

    for (int ks = 0; ks < 4; ks++) {
        short8 bf[8];
        #pragma unroll
        for (int cj = 0; cj < 8; cj++)
            bf[cj] = ((const short8*)WF)[(ks*8 + cj)*64 + lane];
        const int ko = ks*32 + quad*8;
        #pragma unroll
        for (int ti = 0; ti < 2; ti++) {
            const int pr = ti ? pr1 : pr0;
            const int m  = ti ? nid1 : nid0;
            const float* qp = q  + (size_t)pr*DS + ko;
            const float* kp = km + (size_t)m*DS + ko;
            const float* xp = xe + (size_t)m*DS + ko;
            floatx4 qa = *(const floatx4*)qp,       qb = *(const floatx4*)(qp+4);
            floatx4 ka = *(const floatx4*)kp,       kb = *(const floatx4*)(kp+4);
            floatx4 xa = *(const floatx4*)xp,       xb = *(const floatx4*)(xp+4);
            short8 af;
            #pragma unroll
            for (int j = 0; j < 4; j++) af[j]   = (short)f2bf(qa[j] - ka[j] + xa[j]);
            #pragma unroll
            for (int j = 0; j < 4; j++) af[4+j] = (short)f2bf(qb[j] - kb[j] + xb[j]);
            #pragma unroll
            for (int cj = 0; cj < 8; cj++)
                acc[ti][cj] = __builtin_amdgcn_mfma_f32_16x16x32_bf16(af, bf[cj], acc[ti][cj], 0, 0, 0);
        }
    }

    #pragma unroll
    for (int cj = 0; cj < 8; cj++) {
        const float bb = b1[cj*16 + c];
        float s = 0.f, ss = 0.f;
        #pragma unroll
        for (int ti = 0; ti < 2; ti++)
            #pragma unroll
            for (int p = 0; p < 4; p++) {
                float v = acc[ti][cj][p] + bb;
                s += v; ss += v*v;
                int lr = w*32 + ti*16 + quad*4 + p;
                outT[lr*128 + cj*16 + c] = f2bf(v);
            }
        s  += __shfl_xor(s, 16);  s  += __shfl_xor(s, 32);
        ss += __shfl_xor(ss, 16); ss += __shfl_xor(ss, 32);
        if (quad == 0) {
            atomicAdd(&sstat[cj*16 + c], s);
            atomicAdd(&sstat[128 + cj*16 + c], ss);
        }
    }
    __syncthreads();
    unsigned short* gdst = hpre + (size_t)blockIdx.x * 128 * 128;
    #pragma unroll
    for (int i = 0; i < 8; i++)
        ((uint4*)gdst)[t + 256*i] = ((const uint4*)outT)[t + 256*i];
    if (t < 128) atomicAdd(&sums[t], sstat[t]);
    else         atomicAdd(&sumsq[t - 128], sstat[t]);
}

// ---------------------------- MFMA attn: bn+relu -> sim GEMM -> softmax -> agg
__global__ __launch_bounds__(256) void k_attn2(
    const unsigned short* __restrict__ hpre, const float* __restrict__ scale_h,
    const float* __restrict__ shift_h, const unsigned short* __restrict__ W2sw,
    const float* __restrict__ v, const float* __restrict__ xe,
    const int* __restrict__ nidx, float* __restrict__ agg)
{
    __shared__ unsigned short WF[16384];
    const int t = threadIdx.x;
    #pragma unroll
    for (int i = 0; i < 8; i++)
        ((uint4*)WF)[t + 256*i] = ((const uint4*)W2sw)[t + 256*i];
    __syncthreads();

    const int w = t >> 6, lane = t & 63;
    const int gp = blockIdx.x * 4 + w;
    const int quad = lane >> 4, c = lane & 15;

    floatx4 acc[8];
    #pragma unroll
    for (int cj = 0; cj < 8; cj++) acc[cj] = (floatx4){0.f, 0.f, 0.f, 0.f};

    for (int ks = 0; ks < 4; ks++) {
        const int ko = ks*32 + quad*8;
        const unsigned short* hp = hpre + ((size_t)gp*16 + c)*DS + ko;
        uint4 hv = *(const uint4*)hp;
        floatx4 sc0 = *(const floatx4*)(scale_h + ko);
        floatx4 sc1 = *(const floatx4*)(scale_h + ko + 4);
        floatx4 sh0 = *(const floatx4*)(shift_h + ko);
        floatx4 sh1 = *(const floatx4*)(shift_h + ko + 4);
        unsigned int hw[4] = {hv.x, hv.y, hv.z, hv.w};
        short8 af;
        #pragma unroll
        for (int j = 0; j < 4; j++) {
            unsigned short u0 = (unsigned short)(hw[j] & 0xffffu);
            unsigned short u1 = (unsigned short)(hw[j] >> 16);
            float f0 = fmaxf(fmaf(bf2f(u0), (j<2)?sc0[2*j]:sc1[2*j-4],   (j<2)?sh0[2*j]:sh1[2*j-4]),   0.f);
            float f1 = fmaxf(fmaf(bf2f(u1), (j<2)?sc0[2*j+1]:sc1[2*j-3], (j<2)?sh0[2*j+1]:sh1[2*j-3]), 0.f);
            af[2*j]   = (short)f2bf(f0);
            af[2*j+1] = (short)f2bf(f1);
        }
        #pragma unroll
        for (int cj = 0; cj < 8; cj++) {
            short8 bfv = ((const short8*)WF)[(ks*8 + cj)*64 + lane];
            acc[cj] = __builtin_amdgcn_mfma_f32_16x16x32_bf16(af, bfv, acc[cj], 0, 0, 0);
        }
    }

    int nid[4];
    #pragma unroll
    for (int p = 0; p < 4; p++) nid[p] = nidx[gp*16 + quad*4 + p];

    #pragma unroll
    for (int cj = 0; cj < 8; cj++) {
        float m4 = fmaxf(fmaxf(acc[cj][0], acc[cj][1]), fmaxf(acc[cj][2], acc[cj][3]));
        m4 = fmaxf(m4, __shfl_xor(m4, 16));
        m4 = fmaxf(m4, __shfl_xor(m4, 32));
        float e[4]; float s4 = 0.f;
        #pragma unroll
        for (int p = 0; p < 4; p++) { e[p] = __expf(acc[cj][p] - m4); s4 += e[p]; }
        s4 += __shfl_xor(s4, 16); s4 += __shfl_xor(s4, 32);
        const float inv = 1.f / s4;
        const int col = cj*16 + c;
        float a = 0.f;
        #pragma unroll
        for (int p = 0; p < 4; p++) {
            const int m = nid[p];
            a = fmaf(e[p]*inv, v[(size_t)m*DS + col] + xe[(size_t)m*DS + col], a);
        }
        a += __shfl_xor(a, 16); a += __shfl_xor(a, 32);
        if (quad == 0) agg[(size_t)gp*DS + col] = a;
    }
}

__global__ void k_finalize(const float* __restrict__ sums, const float* __restrict__ sumsq,
                           const float* __restrict__ g, const float* __restrict__ bt,
                           int M, int N, float* __restrict__ scale, float* __restrict__ shift)
{
    int c = blockIdx.x * blockDim.x + threadIdx.x;
    if (c < N) {
        float m  = sums[c] / (float)M;
        float var = sumsq[c] / (float)M - m*m;
        float sc = g[c] * rsqrtf(var + 1e-5f);
        scale[c] = sc;
        shift[c] = bt[c] - m * sc;
    }
}

// bn+relu with inline finalize (scale/shift recomputed per element — mem-bound)
__global__ __launch_bounds__(256) void k_bnrelu(
    const float* __restrict__ X, const float* __restrict__ sums,
    const float* __restrict__ sumsq, const float* __restrict__ g,
    const float* __restrict__ bt, float invM,
    float* __restrict__ Y, size_t total, int N)
{
    size_t i = (size_t)blockIdx.x * 256 + threadIdx.x;
    if (i < total) {
        int c = (int)(i & (size_t)(N - 1));
        float m  = sums[c] * invM;
        float var = sumsq[c] * invM - m*m;
        float sc = g[c] * rsqrtf(var + 1e-5f);
        float sh = bt[c] - m * sc;
        Y[i] = fmaxf(fmaf(X[i], sc, sh), 0.f);
    }
}

// --------------- cooperative radix-select top-K, d^2 keys, packed float4 pts
// rounds on float-d2 bits: [31:20] (4096 bins, fused with distance), [19:8], [7:0]
// EPI 0: write nidx (K=16).  EPI 1: inverse-distance interp (K=8) -> xi.
template<int NCAND, int KSEL, int EPI>
__global__ __launch_bounds__(256) void k_sel(
    const float4* __restrict__ qpts4, const float4* __restrict__ cpts4,
    int* __restrict__ nidx, const float* __restrict__ x2, float* __restrict__ xi)
{
    __shared__ unsigned hist[4096];
    __shared__ unsigned skey[64];
    __shared__ unsigned sidx[64];
    __shared__ float    swt[KSEL];
    __shared__ unsigned wpart[4];
    __shared__ int      sstate[8];   // P,S,cntB,mode,compact-counter,fb-total

    const int gp = blockIdx.x, b = gp >> 12;
    const int t = threadIdx.x, wv = t >> 6, lane = t & 63;
    constexpr int ITER = NCAND / 256;

    const float4 qv = qpts4[gp];
    const float4* pb = cpts4 + (size_t)b*NCAND;

    // zero round-0 histogram
    #pragma unroll
    for (int i2 = 0; i2 < 4; i2++)
        ((uint4*)hist)[t + 256*i2] = (uint4){0u,0u,0u,0u};
    __syncthreads();

    // fused distance + round-0 histogram
    unsigned kreg[ITER];
    #pragma unroll
    for (int it = 0; it < ITER; it++) {
        int j = t + 256*it;
        float4 cv = pb[j];
        float dot = fmaf(qv.z, cv.z, fmaf(qv.y, cv.y, qv.x*cv.x));
        float d2 = fmaxf(fmaf(-2.f, dot, qv.w + cv.w), 0.f);
        unsigned key = __float_as_uint(d2);
        kreg[it] = key;
        atomicAdd(&hist[key >> 20], 1u);
    }
    __syncthreads();

    unsigned P = 0;
    int S = 0, cntB = 0, mode = 0, gsh = 0;
    for (int round = 0; round < 3; round++) {
        const int nb  = (round < 2) ? 4096 : 256;
        const int bpt = nb >> 8;
        const int wb  = (round < 2) ? 12 : 8;
        const int sh  = (round == 0) ? 20 : (round == 1 ? 8 : 0);
        const int psh = (sh + wb) & 31;
        if (round > 0) {
            for (int i2 = t; i2 < (nb >> 2); i2 += 256)
                ((uint4*)hist)[i2] = (uint4){0u,0u,0u,0u};
            __syncthreads();
            #pragma unroll
            for (int it = 0; it < ITER; it++) {
                unsigned key = kreg[it];
                if ((key >> psh) == P)
                    atomicAdd(&hist[(key >> sh) & (nb - 1)], 1u);
            }
            __syncthreads();
        }
        unsigned hv[16]; unsigned tsum = 0;
        if (bpt == 16) {
            #pragma unroll
            for (int qq = 0; qq < 4; qq++) {
                uint4 h4 = ((const uint4*)hist)[t*4 + qq];
                hv[qq*4+0]=h4.x; hv[qq*4+1]=h4.y; hv[qq*4+2]=h4.z; hv[qq*4+3]=h4.w;
            }
            #pragma unroll
            for (int qq = 0; qq < 16; qq++) tsum += hv[qq];
        } else {
            hv[0] = hist[t]; tsum = hv[0];
        }
        unsigned incl = tsum;
        #pragma unroll
        for (int off = 1; off < 64; off <<= 1) {
            unsigned o = (unsigned)__shfl_up((int)incl, off);
            if (lane >= off) incl += o;
        }
        if (lane == 63) wpart[wv] = incl;
        __syncthreads();
        unsigned wbase = 0;
        for (int i2 = 0; i2 < wv; i2++) wbase += wpart[i2];
        const unsigned exclT = wbase + incl - tsum;
        const int need = KSEL - S;
        if ((int)exclT < need && need <= (int)(exclT + tsum)) {
            unsigned cum = exclT;
            for (int i2 = 0; i2 < bpt; i2++) {
                unsigned h = hv[i2];
                if ((int)cum < need && need <= (int)(cum + h)) {
                    unsigned Bbin = (unsigned)(t*bpt + i2);
                    unsigned nP = (round == 0) ? Bbin : ((P << wb) | Bbin);
                    int Snew = S + (int)cum;
                    int tot  = Snew + (int)h;
                    sstate[0] = (int)nP; sstate[1] = Snew; sstate[2] = (int)h;
                    sstate[3] = (tot <= 64) ? 1 : ((round == 2) ? 2 : 0);
                    sstate[4] = 0;
                    break;
                }
                cum += h;
            }
        }
        __syncthreads();
        P = (unsigned)sstate[0]; S = sstate[1]; cntB = sstate[2]; mode = sstate[3];
        gsh = sh;
        if (mode) break;
    }

    int total;
    if (mode != 2) {
        // unordered block compaction (bitonic sort restores (key,idx) order)
        const unsigned long long lmask = (1ull << lane) - 1ull;
        #pragma unroll
        for (int it = 0; it < ITER; it++) {
            int j = t + 256*it;
            unsigned key = kreg[it];
            bool f = ((key >> gsh) <= P);
            unsigned long long bal = __ballot(f);
            int wcnt = __popcll(bal);
            int base = 0;
            if (lane == 0 && wcnt) base = atomicAdd((unsigned*)&sstate[4], (unsigned)wcnt);
            base = __shfl(base, 0);
            if (f) {
                int pos = base + __popcll(bal & lmask);
                skey[pos] = key; sidx[pos] = (unsigned)j;
            }
        }
        total = S + cntB;
    } else {
        // exact 32-bit tie overflow (rare): wave-0 serial recompute, ties by index
        if (t < 64) {
            const unsigned long long lmask = (1ull << lane) - 1ull;
            int cnt = 0;
            for (int pass = 0; pass < 2; pass++) {
                for (int it = 0; it < NCAND/64; it++) {
                    int j = lane + 64*it;
                    float4 cv = pb[j];
                    float dot = fmaf(qv.z, cv.z, fmaf(qv.y, cv.y, qv.x*cv.x));
                    float d2 = fmaxf(fmaf(-2.f, dot, qv.w + cv.w), 0.f);
                    unsigned key = __float_as_uint(d2);
                    bool f = pass ? (key == P) : (key < P);
                    unsigned long long bal = __ballot(f);
                    if (f) {
                        int pos = cnt + __popcll(bal & lmask);
                        if (pos < 64) { skey[pos] = key; sidx[pos] = (unsigned)j; }
                    }
                    cnt += __popcll(bal);
                }
            }
            if (lane == 0) sstate[5] = min(cnt, 64);
        }
        __syncthreads();
        total = sstate[5];
    }
    __syncthreads();

    // 64-lane bitonic sort on wave 0: (key, idx) ascending
    if (t < 64) {
        unsigned long long v = ~0ull;
        if (lane < total) v = (((unsigned long long)skey[lane]) << 32) | sidx[lane];
        #pragma unroll
        for (int k = 2; k <= 64; k <<= 1) {
            #pragma unroll
            for (int jj = k >> 1; jj > 0; jj >>= 1) {
                unsigned long long p = shfl_xor_u64(v, jj);
                bool up = ((lane & k) == 0);
                bool takeMin = (((lane & jj) == 0) == up);
                bool pl = p < v;
                v = (takeMin == pl) ? p : v;
            }
        }
        if (EPI == 0) {
            if (lane < KSEL)
                nidx[gp*KSEL + lane] = b*NCAND + (int)(v & 0xffffffffull);
        } else {
            float w = 0.f;
            if (lane < KSEL)
                w = 1.f / (sqrtf(__uint_as_float((unsigned)(v >> 32))) + 1e-8f);
            float ws = w;
            ws += __shfl_xor(ws, 1); ws += __shfl_xor(ws, 2); ws += __shfl_xor(ws, 4);
            if (lane < KSEL) {
                swt[lane]  = w / ws;
                sidx[lane] = (unsigned)(v & 0xffffffffull);
            }
        }
    }
    if (EPI == 1) {
        __syncthreads();
        if (t < DS) {
            const float* x2b = x2 + (size_t)b*NCAND*DS;
            float a = 0.f;
            #pragma unroll
            for (int r = 0; r < KSEL; r++)
                a = fmaf(swt[r], x2b[(size_t)sidx[r]*DS + t], a);
            xi[(size_t)gp*DS + t] = a;
        }
    }
}

// ---------------------------------------------------------------- launch
extern "C" void kernel_launch(void* const* d_in, const int* in_sizes, int n_in,
                              void* d_out, int out_size, void* d_ws, size_t ws_size,
                              hipStream_t stream)
{
    const float* p1 = (const float*)d_in[0];
    const float* x1 = (const float*)d_in[1];
    const int*   o1 = (const int*)d_in[2];
    const float* p2 = (const float*)d_in[3];
    const float* x2 = (const float*)d_in[4];
    const float* W_dense = (const float*)d_in[7];
    const float* b_dense = (const float*)d_in[8];
    const float* g_dense = (const float*)d_in[9];
    const float* bt_dense= (const float*)d_in[10];
    const float* Wq = (const float*)d_in[11];
    const float* Wk = (const float*)d_in[12];
    const float* Wv = (const float*)d_in[13];
    const float* W1 = (const float*)d_in[14];
    const float* b1 = (const float*)d_in[15];
    const float* g1 = (const float*)d_in[16];
    const float* bt1= (const float*)d_in[17];
    const float* W2 = (const float*)d_in[18];
    const float* W_out = (const float*)d_in[20];
    const float* b_out = (const float*)d_in[21];
    const float* g_out = (const float*)d_in[22];
    const float* bt_out= (const float*)d_in[23];

    float* ws   = (float*)d_ws;
    unsigned short* hpre = (unsigned short*)(ws + OFF_HPRE);
    unsigned short* wts  = (unsigned short*)(ws + OFF_WTS);
    float* tmp  = ws + OFF_TMP;
    float* xd   = ws + OFF_XD;
    float* xi   = ws + OFF_XI;
    float* qm   = ws + OFF_Q;
    float* outp = ws + OFF_OUTP;
    int*   nidx = (int*)(ws + OFF_NIDX);
    float* stat = ws + OFF_STAT;
    float4* p1q = (float4*)(ws + OFF_P1Q);
    float4* p2q = (float4*)(ws + OFF_P2Q);
    float* km   = ws + OFF_K;
    float* vm   = ws + OFF_V;
    float* sums_d = stat,      *sumsq_d = stat+256;
    float* sums_h = stat+1024, *sumsq_h = stat+1280, *scale_h = stat+1536, *shift_h = stat+1792;
    float* sums_o = stat+2048, *sumsq_o = stat+2304;
    float* out = (float*)d_out;

    // prolog: copyout + stat zero + point packing
    k_prolog<<<(PRO_TOTAL + 255)/256, 256, 0, stream>>>(p1, o1, p2, out, stat, p1q, p2q);

    // fused weight swizzles (hi/lo planes)
    SwzParams sp;
    sp.W[0]=W_dense; sp.W[1]=Wq; sp.W[2]=Wk; sp.W[3]=Wv; sp.W[4]=W1; sp.W[5]=W2; sp.W[6]=W_out;
    sp.hi[0]=wts+WDH; sp.hi[1]=wts+WQH; sp.hi[2]=wts+WKH; sp.hi[3]=wts+WVH;
    sp.hi[4]=wts+W1H; sp.hi[5]=wts+W2H; sp.hi[6]=wts+WOH;
    sp.lo[0]=wts+WDL; sp.lo[1]=wts+WQL; sp.lo[2]=wts+WKL; sp.lo[3]=wts+WVL;
    sp.lo[4]=wts+W1L; sp.lo[5]=wts+W2L; sp.lo[6]=wts+WOL;
    sp.N[0]=128; sp.N[1]=128; sp.N[2]=128; sp.N[3]=128; sp.N[4]=128; sp.N[5]=128; sp.N[6]=256;
    sp.fid0[0]=0; sp.fid0[1]=16; sp.fid0[2]=48; sp.fid0[3]=80; sp.fid0[4]=112;
    sp.fid0[5]=144; sp.fid0[6]=176; sp.fid0[7]=272;
    k_swizzle_all<<<272, 64, 0, stream>>>(sp);

    // dense_mlp (stats fused) -> bn+relu (finalize inline)
    k_gemm_mf<128,64,0,1><<<M1/64, 256, 0, stream>>>(x1, wts+WDH, wts+WDL, b_dense, tmp,
        nullptr, sums_d, sumsq_d);
    k_bnrelu<<<(M1*DS)/256, 256, 0, stream>>>(tmp, sums_d, sumsq_d, g_dense, bt_dense,
        1.f/(float)M1, xd, (size_t)M1*DS, DS);

    // interpolation (radix select on d^2, K=8)
    k_sel<NN2, KI, 1><<<M1, 256, 0, stream>>>(p1q, p2q, nullptr, x2, xi);

    // q, k, v projections — one launch
    k_gemm_mf<128,128,3,0><<<dim3(M1/64,3), 256, 0, stream>>>(xd, wts+WQH, wts+WQL,
        nullptr, qm, xi, nullptr, nullptr);

    // kNN-16 (radix select on d^2)
    k_sel<NN1, KN, 0><<<M1, 256, 0, stream>>>(p1q, p1q, nidx, nullptr, nullptr);

    // h-GEMM (MFMA, fused BN stats) -> hpre bf16
    k_gemm_h<<<MH/128, 256, 0, stream>>>(qm, km, xd, nidx, wts+W1H, b1, hpre, sums_h, sumsq_h);
    k_finalize<<<1, 256, 0, stream>>>(sums_h, sumsq_h, g1, bt1, MH, DS, scale_h, shift_h);

    // attn (MFMA)
    k_attn2<<<M1/4, 256, 0, stream>>>(hpre, scale_h, shift_h, wts+W2H, vm, xd, nidx, tmp);

    // output mlp (stats fused) -> bn+relu (finalize inline)
    k_gemm_mf<256,192,2,1><<<M1/64, 256, 0, stream>>>(tmp, wts+WOH, wts+WOL, b_out, outp,
        x1, sums_o, sumsq_o);
    k_bnrelu<<<(M1*DOUT)/256, 256, 0, stream>>>(outp, sums_o, sumsq_o, g_out, bt_out,
        1.f/(float)M1, out + OUT_X, (size_t)M1*DOUT, DOUT);
}

// Round 8
// 435.095 us; speedup vs baseline: 1.5703x; 1.0589x over previous
//
#include <hip/hip_runtime.h>
#include <math.h>

#define BB 4
#define NN1 4096
#define NN2 1024
#define DS 128
#define DD 64
#define DOUT 256
#define M1 16384        // BB*NN1
#define MH 262144       // M1*16
#define KCAT 192        // DS+DD
#define KI 8            // interp k
#define KN 16           // neighbor k

#define OUT_P1 49152
#define OUT_X  49152
#define OUT_O1 4243456

#define KSCALE 268435456.f   // 2^28: fixed-point key scale for d^2 (<4)

// ---- workspace layout (float offsets) ----
static const size_t OFF_HPRE = 0;                      // bf16 MH*DS
static const size_t OFF_WTS  = 16777216;               // swizzled weights (hi/lo)
static const size_t OFF_TMP  = 33554432;
static const size_t OFF_XD   = OFF_TMP  + 2097152;
static const size_t OFF_XI   = OFF_XD   + 2097152;
static const size_t OFF_Q    = OFF_XI   + 2097152;
static const size_t OFF_K    = OFF_Q    + 2097152;
static const size_t OFF_V    = OFF_K    + 2097152;
static const size_t OFF_OUTP = OFF_V    + 2097152;
static const size_t OFF_NIDX = OFF_OUTP + 4194304;
static const size_t OFF_STAT = OFF_NIDX + 262144;      // 3072 floats
static const size_t OFF_P1Q  = OFF_STAT + 4096;        // 16384 float4
static const size_t OFF_P2Q  = OFF_P1Q  + 65536;       // 4096 float4

// ushort offsets inside the weights region
#define WDH 0
#define WDL 8192
#define WQH 16384
#define WQL 32768
#define WKH 49152
#define WKL 65536
#define WVH 81920
#define WVL 98304
#define W1H 114688
#define W1L 131072
#define W2H 147456
#define W2L 163840
#define WOH 180224
#define WOL 229376

typedef __attribute__((ext_vector_type(8))) short short8;
typedef __attribute__((ext_vector_type(4))) float floatx4;

__device__ inline unsigned short f2bf(float f) {
    union { float f; unsigned int u; } x; x.f = f;
    unsigned int r = x.u + 0x7fffu + ((x.u >> 16) & 1u);
    return (unsigned short)(r >> 16);
}
__device__ inline float bf2f(unsigned short h) {
    union { unsigned int u; float f; } x; x.u = ((unsigned int)h) << 16;
    return x.f;
}
__device__ inline unsigned long long shfl_xor_u64(unsigned long long v, int m) {
    unsigned lo = (unsigned)v, hi = (unsigned)(v >> 32);
    lo = (unsigned)__shfl_xor((int)lo, m);
    hi = (unsigned)__shfl_xor((int)hi, m);
    return ((unsigned long long)hi << 32) | lo;
}

// --------------- prolog: copy p1/o1 to out, zero stats, pack points as float4
#define PRO_STAT  (OUT_P1 + BB)          // 49156
#define PRO_PACK  (PRO_STAT + 3072)      // 52228
#define PRO_TOTAL (PRO_PACK + M1 + BB*NN2)
__global__ void k_prolog(const float* __restrict__ p1, const int* __restrict__ o1,
                         const float* __restrict__ p2, float* __restrict__ out,
                         float* __restrict__ stat, float4* __restrict__ p1q,
                         float4* __restrict__ p2q)
{
    int i = blockIdx.x * 256 + threadIdx.x;
    if (i < OUT_P1) out[i] = p1[i];
    else if (i < PRO_STAT) out[OUT_O1 + (i - OUT_P1)] = (float)o1[i - OUT_P1];
    else if (i < PRO_PACK) stat[i - PRO_STAT] = 0.f;
    else if (i < PRO_TOTAL) {
        int j = i - PRO_PACK;
        const float* src; float4* dst; int jj;
        if (j < M1) { src = p1; dst = p1q; jj = j; }
        else        { src = p2; dst = p2q; jj = j - M1; }
        float x = src[jj*3+0], y = src[jj*3+1], z = src[jj*3+2];
        float n = fmaf(z, z, fmaf(y, y, x*x));
        dst[jj] = make_float4(x, y, z, n);
    }
}

// --------------------------- fused W swizzle (all 7 weights), hi+lo planes
struct SwzParams {
    const float* W[7];
    unsigned short* hi[7];
    unsigned short* lo[7];
    int N[7];
    int fid0[8];
};
__global__ __launch_bounds__(64) void k_swizzle_all(SwzParams p)
{
    int blk = blockIdx.x, lane = threadIdx.x;
    int seg = 0;
    #pragma unroll
    for (int i = 1; i < 7; i++) if (blk >= p.fid0[i]) seg = i;
    int fid = blk - p.fid0[seg];
    const float* W = p.W[seg];
    int N = p.N[seg];
    int ncj = N >> 4;
    int slab = fid / ncj, cj = fid - slab*ncj;
    int n  = cj*16 + (lane & 15);
    int k0 = slab*32 + (lane >> 4)*8;
    unsigned int oh[8], ol[8];
    #pragma unroll
    for (int j = 0; j < 8; j++) {
        float v = W[(size_t)(k0 + j) * N + n];
        unsigned short h = f2bf(v);
        oh[j] = h;
        ol[j] = f2bf(v - bf2f(h));
    }
    uint4 ph, pl;
    ph.x = oh[0] | (oh[1] << 16); ph.y = oh[2] | (oh[3] << 16);
    ph.z = oh[4] | (oh[5] << 16); ph.w = oh[6] | (oh[7] << 16);
    pl.x = ol[0] | (ol[1] << 16); pl.y = ol[2] | (ol[3] << 16);
    pl.z = ol[4] | (ol[5] << 16); pl.w = ol[6] | (ol[7] << 16);
    ((uint4*)p.hi[seg])[fid*64 + lane] = ph;
    ((uint4*)p.lo[seg])[fid*64 + lane] = pl;
}

// ----------------------------- split-bf16 MFMA GEMM (near-fp32 via hi/lo x 3)
// mode 0: A plain (stride K). mode 2: A = concat(Amat, aux[.,0:64]).
// mode 3: qkv — blockIdx.y in {0,1,2}: A = (y==0?Amat:aux), W/C offset by y.
// STATS: fuse BN column sums/sumsq (post-bias) via LDS + global atomics
template<int N, int K, int MODE, int STATS>
__global__ __launch_bounds__(256) void k_gemm_mf(
    const float* __restrict__ Amat, const unsigned short* __restrict__ Whi,
    const unsigned short* __restrict__ Wlo, const float* __restrict__ bias,
    float* __restrict__ C, const float* __restrict__ aux,
    float* __restrict__ sums, float* __restrict__ sumsq)
{
    __shared__ float sstat[STATS ? 2*N : 1];
    const int t = threadIdx.x, w = t >> 6, lane = t & 63;
    const int quad = lane >> 4, c = lane & 15;
    const int row = blockIdx.x*64 + w*16 + c;
    const int sA = (MODE == 2) ? DS : K;
    constexpr int nslab = K >> 5;
    constexpr int ncj = N >> 4;
    const int seg = (MODE == 3) ? blockIdx.y : 0;
    const float* Abase = (MODE == 3 && seg > 0) ? aux : Amat;
    const unsigned short* WhiS = Whi + (size_t)seg*32768;
    const unsigned short* WloS = Wlo + (size_t)seg*32768;
    float* CS = C + (size_t)seg*2097152;
    if (STATS) {
        for (int i = t; i < 2*N; i += 256) sstat[i] = 0.f;
        __syncthreads();
    }
    floatx4 acc[ncj];
    #pragma unroll
    for (int cj = 0; cj < ncj; cj++) acc[cj] = (floatx4){0.f,0.f,0.f,0.f};

    #pragma unroll
    for (int slab = 0; slab < nslab; slab++) {
        const int kk = slab*32 + quad*8;
        const float* src;
        if (MODE == 2 && kk >= DS) src = aux + (size_t)row*DD + (kk - DS);
        else                       src = Abase + (size_t)row*sA + kk;
        floatx4 va = *(const floatx4*)src;
        floatx4 vb = *(const floatx4*)(src + 4);
        short8 ahi, alo;
        #pragma unroll
        for (int j = 0; j < 4; j++) {
            unsigned short h = f2bf(va[j]);
            ahi[j] = (short)h; alo[j] = (short)f2bf(va[j] - bf2f(h));
        }
        #pragma unroll
        for (int j = 0; j < 4; j++) {
            unsigned short h = f2bf(vb[j]);
            ahi[4+j] = (short)h; alo[4+j] = (short)f2bf(vb[j] - bf2f(h));
        }
        const short8* bh = (const short8*)WhiS + (size_t)slab*ncj*64;
        const short8* bl = (const short8*)WloS + (size_t)slab*ncj*64;
        #pragma unroll
        for (int cj = 0; cj < ncj; cj++) {
            short8 bhv = bh[cj*64 + lane];
            short8 blv = bl[cj*64 + lane];
            acc[cj] = __builtin_amdgcn_mfma_f32_16x16x32_bf16(alo, bhv, acc[cj], 0, 0, 0);
            acc[cj] = __builtin_amdgcn_mfma_f32_16x16x32_bf16(ahi, blv, acc[cj], 0, 0, 0);
            acc[cj] = __builtin_amdgcn_mfma_f32_16x16x32_bf16(ahi, bhv, acc[cj], 0, 0, 0);
        }
    }
    const int rbase = blockIdx.x*64 + w*16 + quad*4;
    #pragma unroll
    for (int cj = 0; cj < ncj; cj++) {
        const float bb = bias ? bias[cj*16 + c] : 0.f;
        float s = 0.f, ss = 0.f;
        #pragma unroll
        for (int p = 0; p < 4; p++) {
            float v = acc[cj][p] + bb;
            CS[(size_t)(rbase + p)*N + cj*16 + c] = v;
            if (STATS) { s += v; ss += v*v; }
        }
        if (STATS) {
            s  += __shfl_xor(s, 16);  s  += __shfl_xor(s, 32);
            ss += __shfl_xor(ss, 16); ss += __shfl_xor(ss, 32);
            if (quad == 0) {
                atomicAdd(&sstat[cj*16 + c], s);
                atomicAdd(&sstat[N + cj*16 + c], ss);
            }
        }
    }
    if (STATS) {
        __syncthreads();
        for (int i = t; i < N; i += 256) {
            atomicAdd(&sums[i],  sstat[i]);
            atomicAdd(&sumsq[i], sstat[N + i]);
        }
    }
}

// ------------------------------------------- MFMA h-GEMM + fused BN stats
__global__ __launch_bounds__(256) void k_gemm_h(
    const float* __restrict__ q, const float* __restrict__ km,
    const float* __restrict__ xe, const int* __restrict__ nidx,
    const unsigned short* __restrict__ W1sw, const float* __restrict__ b1,
    unsigned short* __restrict__ hpre,
    float* __restrict__ sums, float* __restrict__ sumsq)
{
    __shared__ unsigned short WF[16384];
    __shared__ unsigned short outT[128*128];
    __shared__ float sstat[256];
    const int t = threadIdx.x;
    const int w = t >> 6, lane = t & 63;
    sstat[t] = 0.f;
    #pragma unroll
    for (int i = 0; i < 8; i++)
        ((uint4*)WF)[t + 256*i] = ((const uint4*)W1sw)[t + 256*i];
    __syncthreads();

    const int quad = lane >> 4, c = lane & 15;
    const int r0 = blockIdx.x * 128 + w * 32;
    const int nid0 = nidx[r0 + c];
    const int nid1 = nidx[r0 + 16 + c];
    const int pr0 = r0 >> 4;
    const int pr1 = pr0 + 1;

    floatx4 acc[2][8];
    #pragma unroll
    for (int ti = 0; ti < 2; ti++)
        #pragma unroll
        for (int cj = 0; cj < 8; cj++)
            acc[ti][cj] = (floatx4){0.f, 0.f, 0.f, 0.f};

    for (int ks = 0; ks < 4; ks++) {
        short8 bf[8];
        #pragma unroll
        for (int cj = 0; cj < 8; cj++)
            bf[cj] = ((const short8*)WF)[(ks*8 + cj)*64 + lane];
        const int ko = ks*32 + quad*8;
        #pragma unroll
        for (int ti = 0; ti < 2; ti++) {
            const int pr = ti ? pr1 : pr0;
            const int m  = ti ? nid1 : nid0;
            const float* qp = q  + (size_t)pr*DS + ko;
            const float* kp = km + (size_t)m*DS + ko;
            const float* xp = xe + (size_t)m*DS + ko;
            floatx4 qa = *(const floatx4*)qp,       qb = *(const floatx4*)(qp+4);
            floatx4 ka = *(const floatx4*)kp,       kb = *(const floatx4*)(kp+4);
            floatx4 xa = *(const floatx4*)xp,       xb = *(const floatx4*)(xp+4);
            short8 af;
            #pragma unroll
            for (int j = 0; j < 4; j++) af[j]   = (short)f2bf(qa[j] - ka[j] + xa[j]);
            #pragma unroll
            for (int j = 0; j < 4; j++) af[4+j] = (short)f2bf(qb[j] - kb[j] + xb[j]);
            #pragma unroll
            for (int cj = 0; cj < 8; cj++)
                acc[ti][cj] = __builtin_amdgcn_mfma_f32_16x16x32_bf16(af, bf[cj], acc[ti][cj], 0, 0, 0);
        }
    }

    #pragma unroll
    for (int cj = 0; cj < 8; cj++) {
        const float bb = b1[cj*16 + c];
        float s = 0.f, ss = 0.f;
        #pragma unroll
        for (int ti = 0; ti < 2; ti++)
            #pragma unroll
            for (int p = 0; p < 4; p++) {
                float v = acc[ti][cj][p] + bb;
                s += v; ss += v*v;
                int lr = w*32 + ti*16 + quad*4 + p;
                outT[lr*128 + cj*16 + c] = f2bf(v);
            }
        s  += __shfl_xor(s, 16);  s  += __shfl_xor(s, 32);
        ss += __shfl_xor(ss, 16); ss += __shfl_xor(ss, 32);
        if (quad == 0) {
            atomicAdd(&sstat[cj*16 + c], s);
            atomicAdd(&sstat[128 + cj*16 + c], ss);
        }
    }
    __syncthreads();
    unsigned short* gdst = hpre + (size_t)blockIdx.x * 128 * 128;
    #pragma unroll
    for (int i = 0; i < 8; i++)
        ((uint4*)gdst)[t + 256*i] = ((const uint4*)outT)[t + 256*i];
    if (t < 128) atomicAdd(&sums[t], sstat[t]);
    else         atomicAdd(&sumsq[t - 128], sstat[t]);
}

// --------- MFMA attn: inline BN finalize -> bn+relu -> sim -> softmax -> agg
__global__ __launch_bounds__(256) void k_attn2(
    const unsigned short* __restrict__ hpre, const float* __restrict__ sums_h,
    const float* __restrict__ sumsq_h, const float* __restrict__ g1,
    const float* __restrict__ bt1, const unsigned short* __restrict__ W2sw,
    const float* __restrict__ v, const float* __restrict__ xe,
    const int* __restrict__ nidx, float* __restrict__ agg)
{
    __shared__ unsigned short WF[16384];
    __shared__ float s_sc[DS], s_sh[DS];
    const int t = threadIdx.x;
    #pragma unroll
    for (int i = 0; i < 8; i++)
        ((uint4*)WF)[t + 256*i] = ((const uint4*)W2sw)[t + 256*i];
    if (t < DS) {
        const float invM = 1.f / (float)MH;
        float m   = sums_h[t] * invM;
        float var = sumsq_h[t] * invM - m*m;
        float sc  = g1[t] * rsqrtf(var + 1e-5f);
        s_sc[t] = sc;
        s_sh[t] = bt1[t] - m * sc;
    }
    __syncthreads();

    const int w = t >> 6, lane = t & 63;
    const int gp = blockIdx.x * 4 + w;
    const int quad = lane >> 4, c = lane & 15;

    floatx4 acc[8];
    #pragma unroll
    for (int cj = 0; cj < 8; cj++) acc[cj] = (floatx4){0.f, 0.f, 0.f, 0.f};

    for (int ks = 0; ks < 4; ks++) {
        const int ko = ks*32 + quad*8;
        const unsigned short* hp = hpre + ((size_t)gp*16 + c)*DS + ko;
        uint4 hv = *(const uint4*)hp;
        floatx4 sc0 = *(const floatx4*)&s_sc[ko];
        floatx4 sc1 = *(const floatx4*)&s_sc[ko + 4];
        floatx4 sh0 = *(const floatx4*)&s_sh[ko];
        floatx4 sh1 = *(const floatx4*)&s_sh[ko + 4];
        unsigned int hw[4] = {hv.x, hv.y, hv.z, hv.w};
        short8 af;
        #pragma unroll
        for (int j = 0; j < 4; j++) {
            unsigned short u0 = (unsigned short)(hw[j] & 0xffffu);
            unsigned short u1 = (unsigned short)(hw[j] >> 16);
            float f0 = fmaxf(fmaf(bf2f(u0), (j<2)?sc0[2*j]:sc1[2*j-4],   (j<2)?sh0[2*j]:sh1[2*j-4]),   0.f);
            float f1 = fmaxf(fmaf(bf2f(u1), (j<2)?sc0[2*j+1]:sc1[2*j-3], (j<2)?sh0[2*j+1]:sh1[2*j-3]), 0.f);
            af[2*j]   = (short)f2bf(f0);
            af[2*j+1] = (short)f2bf(f1);
        }
        #pragma unroll
        for (int cj = 0; cj < 8; cj++) {
            short8 bfv = ((const short8*)WF)[(ks*8 + cj)*64 + lane];
            acc[cj] = __builtin_amdgcn_mfma_f32_16x16x32_bf16(af, bfv, acc[cj], 0, 0, 0);
        }
    }

    int nid[4];
    #pragma unroll
    for (int p = 0; p < 4; p++) nid[p] = nidx[gp*16 + quad*4 + p];

    #pragma unroll
    for (int cj = 0; cj < 8; cj++) {
        float m4 = fmaxf(fmaxf(acc[cj][0], acc[cj][1]), fmaxf(acc[cj][2], acc[cj][3]));
        m4 = fmaxf(m4, __shfl_xor(m4, 16));
        m4 = fmaxf(m4, __shfl_xor(m4, 32));
        float e[4]; float s4 = 0.f;
        #pragma unroll
        for (int p = 0; p < 4; p++) { e[p] = __expf(acc[cj][p] - m4); s4 += e[p]; }
        s4 += __shfl_xor(s4, 16); s4 += __shfl_xor(s4, 32);
        const float inv = 1.f / s4;
        const int col = cj*16 + c;
        float a = 0.f;
        #pragma unroll
        for (int p = 0; p < 4; p++) {
            const int m = nid[p];
            a = fmaf(e[p]*inv, v[(size_t)m*DS + col] + xe[(size_t)m*DS + col], a);
        }
        a += __shfl_xor(a, 16); a += __shfl_xor(a, 32);
        if (quad == 0) agg[(size_t)gp*DS + col] = a;
    }
}

// bn+relu, float4-vectorized, inline finalize (memory-bound)
__global__ __launch_bounds__(256) void k_bnrelu(
    const float4* __restrict__ X, const float* __restrict__ sums,
    const float* __restrict__ sumsq, const float* __restrict__ g,
    const float* __restrict__ bt, float invM,
    float4* __restrict__ Y, size_t total4, int N)
{
    size_t i = (size_t)blockIdx.x * 256 + threadIdx.x;
    if (i < total4) {
        int c = (int)((i*4) & (size_t)(N - 1));
        float4 sm = *(const float4*)(sums + c);
        float4 sq = *(const float4*)(sumsq + c);
        float4 gg = *(const float4*)(g + c);
        float4 bb = *(const float4*)(bt + c);
        float4 x = X[i], y;
        float m0 = sm.x*invM, m1 = sm.y*invM, m2 = sm.z*invM, m3 = sm.w*invM;
        float s0 = gg.x*rsqrtf(sq.x*invM - m0*m0 + 1e-5f);
        float s1 = gg.y*rsqrtf(sq.y*invM - m1*m1 + 1e-5f);
        float s2 = gg.z*rsqrtf(sq.z*invM - m2*m2 + 1e-5f);
        float s3 = gg.w*rsqrtf(sq.w*invM - m3*m3 + 1e-5f);
        y.x = fmaxf(fmaf(x.x, s0, bb.x - m0*s0), 0.f);
        y.y = fmaxf(fmaf(x.y, s1, bb.y - m1*s1), 0.f);
        y.z = fmaxf(fmaf(x.z, s2, bb.z - m2*s2), 0.f);
        y.w = fmaxf(fmaf(x.w, s3, bb.w - m3*s3), 0.f);
        Y[i] = y;
    }
}

// ------- cooperative radix-select top-K, fixed-point d^2 keys (spread bins)
// K = (uint)(d2 * 2^28) < 2^30; rounds on K bits [31:20],[19:8],[7:0]
// EPI 0: write nidx (K=16).  EPI 1: inverse-distance interp (K=8) -> xi.
template<int NCAND, int KSEL, int EPI>
__global__ __launch_bounds__(256) void k_sel(
    const float4* __restrict__ qpts4, const float4* __restrict__ cpts4,
    int* __restrict__ nidx, const float* __restrict__ x2, float* __restrict__ xi)
{
    __shared__ unsigned hist[4096];
    __shared__ unsigned skey[64];
    __shared__ unsigned sidx[64];
    __shared__ float    swt[KSEL];
    __shared__ unsigned wpart[4];
    __shared__ int      sstate[8];   // P,S,cntB,mode,compact-counter,fb-total

    const int gp = blockIdx.x, b = gp >> 12;
    const int t = threadIdx.x, wv = t >> 6, lane = t & 63;
    constexpr int ITER = NCAND / 256;

    const float4 qv = qpts4[gp];
    const float4* pb = cpts4 + (size_t)b*NCAND;

    // zero round-0 histogram
    #pragma unroll
    for (int i2 = 0; i2 < 4; i2++)
        ((uint4*)hist)[t + 256*i2] = (uint4){0u,0u,0u,0u};
    __syncthreads();

    // fused distance + round-0 histogram (fixed-point keys spread the bins)
    unsigned kreg[ITER];
    #pragma unroll
    for (int it = 0; it < ITER; it++) {
        int j = t + 256*it;
        float4 cv = pb[j];
        float dot = fmaf(qv.z, cv.z, fmaf(qv.y, cv.y, qv.x*cv.x));
        float d2 = fmaxf(fmaf(-2.f, dot, qv.w + cv.w), 0.f);
        unsigned key = (unsigned)(d2 * KSCALE);
        kreg[it] = key;
        atomicAdd(&hist[key >> 20], 1u);
    }
    __syncthreads();

    unsigned P = 0;
    int S = 0, cntB = 0, mode = 0, gsh = 0;
    for (int round = 0; round < 3; round++) {
        const int nb  = (round < 2) ? 4096 : 256;
        const int bpt = nb >> 8;
        const int wb  = (round < 2) ? 12 : 8;
        const int sh  = (round == 0) ? 20 : (round == 1 ? 8 : 0);
        const int psh = (sh + wb) & 31;
        if (round > 0) {
            for (int i2 = t; i2 < (nb >> 2); i2 += 256)
                ((uint4*)hist)[i2] = (uint4){0u,0u,0u,0u};
            __syncthreads();
            #pragma unroll
            for (int it = 0; it < ITER; it++) {
                unsigned key = kreg[it];
                if ((key >> psh) == P)
                    atomicAdd(&hist[(key >> sh) & (nb - 1)], 1u);
            }
            __syncthreads();
        }
        unsigned hv[16]; unsigned tsum = 0;
        if (bpt == 16) {
            #pragma unroll
            for (int qq = 0; qq < 4; qq++) {
                uint4 h4 = ((const uint4*)hist)[t*4 + qq];
                hv[qq*4+0]=h4.x; hv[qq*4+1]=h4.y; hv[qq*4+2]=h4.z; hv[qq*4+3]=h4.w;
            }
            #pragma unroll
            for (int qq = 0; qq < 16; qq++) tsum += hv[qq];
        } else {
            hv[0] = hist[t]; tsum = hv[0];
        }
        unsigned incl = tsum;
        #pragma unroll
        for (int off = 1; off < 64; off <<= 1) {
            unsigned o = (unsigned)__shfl_up((int)incl, off);
            if (lane >= off) incl += o;
        }
        if (lane == 63) wpart[wv] = incl;
        __syncthreads();
        unsigned wbase = 0;
        for (int i2 = 0; i2 < wv; i2++) wbase += wpart[i2];
        const unsigned exclT = wbase + incl - tsum;
        const int need = KSEL - S;
        if ((int)exclT < need && need <= (int)(exclT + tsum)) {
            unsigned cum = exclT;
            for (int i2 = 0; i2 < bpt; i2++) {
                unsigned h = hv[i2];
                if ((int)cum < need && need <= (int)(cum + h)) {
                    unsigned Bbin = (unsigned)(t*bpt + i2);
                    unsigned nP = (round == 0) ? Bbin : ((P << wb) | Bbin);
                    int Snew = S + (int)cum;
                    int tot  = Snew + (int)h;
                    sstate[0] = (int)nP; sstate[1] = Snew; sstate[2] = (int)h;
                    sstate[3] = (tot <= 64) ? 1 : ((round == 2) ? 2 : 0);
                    sstate[4] = 0;
                    break;
                }
                cum += h;
            }
        }
        __syncthreads();
        P = (unsigned)sstate[0]; S = sstate[1]; cntB = sstate[2]; mode = sstate[3];
        gsh = sh;
        if (mode) break;
    }

    int total;
    if (mode != 2) {
        // unordered block compaction (bitonic sort restores (key,idx) order)
        const unsigned long long lmask = (1ull << lane) - 1ull;
        #pragma unroll
        for (int it = 0; it < ITER; it++) {
            int j = t + 256*it;
            unsigned key = kreg[it];
            bool f = ((key >> gsh) <= P);
            unsigned long long bal = __ballot(f);
            int wcnt = __popcll(bal);
            int base = 0;
            if (lane == 0 && wcnt) base = atomicAdd((unsigned*)&sstate[4], (unsigned)wcnt);
            base = __shfl(base, 0);
            if (f) {
                int pos = base + __popcll(bal & lmask);
                skey[pos] = key; sidx[pos] = (unsigned)j;
            }
        }
        total = S + cntB;
    } else {
        // >64 keys in one 2^-28 quantum (essentially never): wave-0 serial
        if (t < 64) {
            const unsigned long long lmask = (1ull << lane) - 1ull;
            int cnt = 0;
            for (int pass = 0; pass < 2; pass++) {
                for (int it = 0; it < NCAND/64; it++) {
                    int j = lane + 64*it;
                    float4 cv = pb[j];
                    float dot = fmaf(qv.z, cv.z, fmaf(qv.y, cv.y, qv.x*cv.x));
                    float d2 = fmaxf(fmaf(-2.f, dot, qv.w + cv.w), 0.f);
                    unsigned key = (unsigned)(d2 * KSCALE);
                    bool f = pass ? (key == P) : (key < P);
                    unsigned long long bal = __ballot(f);
                    if (f) {
                        int pos = cnt + __popcll(bal & lmask);
                        if (pos < 64) { skey[pos] = key; sidx[pos] = (unsigned)j; }
                    }
                    cnt += __popcll(bal);
                }
            }
            if (lane == 0) sstate[5] = min(cnt, 64);
        }
        __syncthreads();
        total = sstate[5];
    }
    __syncthreads();

    // 64-lane bitonic sort on wave 0: (key, idx) ascending
    if (t < 64) {
        unsigned long long v = ~0ull;
        if (lane < total) v = (((unsigned long long)skey[lane]) << 32) | sidx[lane];
        #pragma unroll
        for (int k = 2; k <= 64; k <<= 1) {
            #pragma unroll
            for (int jj = k >> 1; jj > 0; jj >>= 1) {
                unsigned long long p = shfl_xor_u64(v, jj);
                bool up = ((lane & k) == 0);
                bool takeMin = (((lane & jj) == 0) == up);
                bool pl = p < v;
                v = (takeMin == pl) ? p : v;
            }
        }
        if (EPI == 0) {
            if (lane < KSEL)
                nidx[gp*KSEL + lane] = b*NCAND + (int)(v & 0xffffffffull);
        } else {
            // recompute exact d for selected candidates (keys are quantized)
            float w = 0.f;
            unsigned si = (unsigned)(v & 0xffffffffull);
            if (lane < KSEL) {
                float4 cv = pb[si];
                float dot = fmaf(qv.z, cv.z, fmaf(qv.y, cv.y, qv.x*cv.x));
                float d2 = fmaxf(fmaf(-2.f, dot, qv.w + cv.w), 0.f);
                w = 1.f / (sqrtf(d2) + 1e-8f);
            }
            float ws = w;
            ws += __shfl_xor(ws, 1); ws += __shfl_xor(ws, 2); ws += __shfl_xor(ws, 4);
            if (lane < KSEL) {
                swt[lane]  = w / ws;
                sidx[lane] = si;
            }
        }
    }
    if (EPI == 1) {
        __syncthreads();
        if (t < DS) {
            const float* x2b = x2 + (size_t)b*NCAND*DS;
            float a = 0.f;
            #pragma unroll
            for (int r = 0; r < KSEL; r++)
                a = fmaf(swt[r], x2b[(size_t)sidx[r]*DS + t], a);
            xi[(size_t)gp*DS + t] = a;
        }
    }
}

// ---------------------------------------------------------------- launch
extern "C" void kernel_launch(void* const* d_in, const int* in_sizes, int n_in,
                              void* d_out, int out_size, void* d_ws, size_t ws_size,
                              hipStream_t stream)
{
    const float* p1 = (const float*)d_in[0];
    const float* x1 = (const float*)d_in[1];
    const int*   o1 = (const int*)d_in[2];
    const float* p2 = (const float*)d_in[3];
    const float* x2 = (const float*)d_in[4];
    const float* W_dense = (const float*)d_in[7];
    const float* b_dense = (const float*)d_in[8];
    const float* g_dense = (const float*)d_in[9];
    const float* bt_dense= (const float*)d_in[10];
    const float* Wq = (const float*)d_in[11];
    const float* Wk = (const float*)d_in[12];
    const float* Wv = (const float*)d_in[13];
    const float* W1 = (const float*)d_in[14];
    const float* b1 = (const float*)d_in[15];
    const float* g1 = (const float*)d_in[16];
    const float* bt1= (const float*)d_in[17];
    const float* W2 = (const float*)d_in[18];
    const float* W_out = (const float*)d_in[20];
    const float* b_out = (const float*)d_in[21];
    const float* g_out = (const float*)d_in[22];
    const float* bt_out= (const float*)d_in[23];

    float* ws   = (float*)d_ws;
    unsigned short* hpre = (unsigned short*)(ws + OFF_HPRE);
    unsigned short* wts  = (unsigned short*)(ws + OFF_WTS);
    float* tmp  = ws + OFF_TMP;
    float* xd   = ws + OFF_XD;
    float* xi   = ws + OFF_XI;
    float* qm   = ws + OFF_Q;
    float* outp = ws + OFF_OUTP;
    int*   nidx = (int*)(ws + OFF_NIDX);
    float* stat = ws + OFF_STAT;
    float4* p1q = (float4*)(ws + OFF_P1Q);
    float4* p2q = (float4*)(ws + OFF_P2Q);
    float* km   = ws + OFF_K;
    float* vm   = ws + OFF_V;
    float* sums_d = stat,      *sumsq_d = stat+256;
    float* sums_h = stat+1024, *sumsq_h = stat+1280;
    float* sums_o = stat+2048, *sumsq_o = stat+2304;
    float* out = (float*)d_out;

    // prolog: copyout + stat zero + point packing
    k_prolog<<<(PRO_TOTAL + 255)/256, 256, 0, stream>>>(p1, o1, p2, out, stat, p1q, p2q);

    // fused weight swizzles (hi/lo planes)
    SwzParams sp;
    sp.W[0]=W_dense; sp.W[1]=Wq; sp.W[2]=Wk; sp.W[3]=Wv; sp.W[4]=W1; sp.W[5]=W2; sp.W[6]=W_out;
    sp.hi[0]=wts+WDH; sp.hi[1]=wts+WQH; sp.hi[2]=wts+WKH; sp.hi[3]=wts+WVH;
    sp.hi[4]=wts+W1H; sp.hi[5]=wts+W2H; sp.hi[6]=wts+WOH;
    sp.lo[0]=wts+WDL; sp.lo[1]=wts+WQL; sp.lo[2]=wts+WKL; sp.lo[3]=wts+WVL;
    sp.lo[4]=wts+W1L; sp.lo[5]=wts+W2L; sp.lo[6]=wts+WOL;
    sp.N[0]=128; sp.N[1]=128; sp.N[2]=128; sp.N[3]=128; sp.N[4]=128; sp.N[5]=128; sp.N[6]=256;
    sp.fid0[0]=0; sp.fid0[1]=16; sp.fid0[2]=48; sp.fid0[3]=80; sp.fid0[4]=112;
    sp.fid0[5]=144; sp.fid0[6]=176; sp.fid0[7]=272;
    k_swizzle_all<<<272, 64, 0, stream>>>(sp);

    // dense_mlp (stats fused) -> bn+relu (finalize inline, float4)
    k_gemm_mf<128,64,0,1><<<M1/64, 256, 0, stream>>>(x1, wts+WDH, wts+WDL, b_dense, tmp,
        nullptr, sums_d, sumsq_d);
    k_bnrelu<<<(M1*DS/4)/256, 256, 0, stream>>>((const float4*)tmp, sums_d, sumsq_d,
        g_dense, bt_dense, 1.f/(float)M1, (float4*)xd, (size_t)M1*DS/4, DS);

    // interpolation (radix select on fixed-point d^2, K=8)
    k_sel<NN2, KI, 1><<<M1, 256, 0, stream>>>(p1q, p2q, nullptr, x2, xi);

    // q, k, v projections — one launch
    k_gemm_mf<128,128,3,0><<<dim3(M1/64,3), 256, 0, stream>>>(xd, wts+WQH, wts+WQL,
        nullptr, qm, xi, nullptr, nullptr);

    // kNN-16 (radix select on fixed-point d^2)
    k_sel<NN1, KN, 0><<<M1, 256, 0, stream>>>(p1q, p1q, nidx, nullptr, nullptr);

    // h-GEMM (MFMA, fused BN stats) -> hpre bf16
    k_gemm_h<<<MH/128, 256, 0, stream>>>(qm, km, xd, nidx, wts+W1H, b1, hpre, sums_h, sumsq_h);

    // attn (MFMA, BN finalize inline)
    k_attn2<<<M1/4, 256, 0, stream>>>(hpre, sums_h, sumsq_h, g1, bt1, wts+W2H, vm, xd, nidx, tmp);

    // output mlp (stats fused) -> bn+relu (finalize inline, float4)
    k_gemm_mf<256,192,2,1><<<M1/64, 256, 0, stream>>>(tmp, wts+WOH, wts+WOL, b_out, outp,
        x1, sums_o, sumsq_o);
    k_bnrelu<<<(M1*DOUT/4)/256, 256, 0, stream>>>((const float4*)outp, sums_o, sumsq_o,
        g_out, bt_out, 1.f/(float)M1, (float4*)(out + OUT_X), (size_t)M1*DOUT/4, DOUT);
}